// Round 1
// baseline (586.708 us; speedup 1.0000x reference)
//
#include <hip/hip_runtime.h>
#include <stdint.h>

#define NQ    9
#define DIM   512
#define HIMG  128
#define WIMG  128
#define HO    126
#define WO    126
#define CCH   8
#define MAXOPS 96

struct Op { uint8_t type, a, b, widx; };   // type: 0=RX 1=RY 2=RZ 3=CNOT(a=ctrl,b=tgt)
struct OpList { int n; Op ops[MAXOPS]; };

__global__ __launch_bounds__(512) void quanv_kernel(
    const float* __restrict__ x, const float* __restrict__ w,
    float* __restrict__ out, OpList ol)
{
  __shared__ float2 st[CCH][DIM];     // per-wave statevector (wave = channel)
  __shared__ float  wsh[2 * NQ];
  __shared__ float  red[CCH][NQ];

  const int tid  = threadIdx.x;
  const int lane = tid & 63;
  const int wv   = tid >> 6;          // channel 0..7
  const int blk  = blockIdx.x;        // site index = ho*WO + wo
  const int ho   = blk / WO;
  const int wo   = blk - ho * WO;

  if (tid < 2 * NQ) wsh[tid] = w[tid];

  // ---- per-patch angles: theta_m = pi * x[c, ho+m/3, wo+m%3]; need cos/sin(theta/2)
  float cs[NQ], sn[NQ];
  {
    const float* xp = x + wv * (HIMG * WIMG) + ho * WIMG + wo;
#pragma unroll
    for (int m = 0; m < NQ; ++m) {
      float v = xp[(m / 3) * WIMG + (m % 3)];
      float h = 1.5707963267948966f * v;      // (pi*v)/2
      sincosf(h, &sn[m], &cs[m]);
    }
  }

  // ---- initial product state: amp(i) = prod_w (bit_{8-w}(i) ? sin_w : cos_w)
  // index i = lane + 64*r :  bits 0..5 = lane (wires 8..3), bits 6..8 = r (wires 2..0)
  float P = 1.f;
#pragma unroll
  for (int p = 0; p < 6; ++p) {
    int wq = 8 - p;
    P *= ((lane >> p) & 1) ? sn[wq] : cs[wq];
  }
#pragma unroll
  for (int r = 0; r < 8; ++r) {
    float g = P;
    g *= ((r     ) & 1) ? sn[2] : cs[2];
    g *= ((r >> 1) & 1) ? sn[1] : cs[1];
    g *= ((r >> 2) & 1) ? sn[0] : cs[0];
    st[wv][lane + (r << 6)] = make_float2(g, 0.f);
  }
  __syncthreads();

  // ---- static random-layer circuit
  for (int k = 0; k < ol.n; ++k) {
    const Op op = ol.ops[k];
    if (op.type < 3) {
      float th = wsh[op.widx] * 0.5f;
      float sh, ch;
      sincosf(th, &sh, &ch);
      float u00x, u00y, u01x, u01y, u10x, u10y, u11x, u11y;
      if (op.type == 0) {        // RX = [[c,-is],[-is,c]]
        u00x = ch;  u00y = 0.f; u01x = 0.f; u01y = -sh;
        u10x = 0.f; u10y = -sh; u11x = ch;  u11y = 0.f;
      } else if (op.type == 1) { // RY = [[c,-s],[s,c]]
        u00x = ch;  u00y = 0.f; u01x = -sh; u01y = 0.f;
        u10x = sh;  u10y = 0.f; u11x = ch;  u11y = 0.f;
      } else {                   // RZ = diag(e^-it/2, e^+it/2)
        u00x = ch;  u00y = -sh; u01x = 0.f; u01y = 0.f;
        u10x = 0.f; u10y = 0.f; u11x = ch;  u11y = sh;
      }
      const int p  = 8 - op.a;   // bit position of the wire
      const int pb = 1 << p;
#pragma unroll
      for (int q = 0; q < 4; ++q) {
        int h  = lane + (q << 6);                       // 256 pair bases
        int i0 = ((h >> p) << (p + 1)) | (h & (pb - 1));
        int i1 = i0 | pb;
        float2 a0 = st[wv][i0];
        float2 a1 = st[wv][i1];
        float2 n0, n1;
        n0.x = u00x * a0.x - u00y * a0.y + u01x * a1.x - u01y * a1.y;
        n0.y = u00x * a0.y + u00y * a0.x + u01x * a1.y + u01y * a1.x;
        n1.x = u10x * a0.x - u10y * a0.y + u11x * a1.x - u11y * a1.y;
        n1.y = u10x * a0.y + u10y * a0.x + u11x * a1.y + u11y * a1.x;
        st[wv][i0] = n0;
        st[wv][i1] = n1;
      }
    } else {                     // CNOT: if bit pc set, flip bit pt (swap pairs)
      const int pc = 8 - op.a;
      const int pt = 8 - op.b;
      const int lo = pc < pt ? pc : pt;
      const int hi = pc < pt ? pt : pc;
#pragma unroll
      for (int q = 0; q < 2; ++q) {
        int h  = lane + (q << 6);                       // 128 swap pairs
        int t1 = ((h  >> lo) << (lo + 1)) | (h  & ((1 << lo) - 1));
        int t2 = ((t1 >> hi) << (hi + 1)) | (t1 & ((1 << hi) - 1));
        int i0 = t2 | (1 << pc);                        // control=1, target=0
        int i1 = i0 | (1 << pt);
        float2 a0 = st[wv][i0];
        float2 a1 = st[wv][i1];
        st[wv][i0] = a1;
        st[wv][i1] = a0;
      }
    }
    __syncthreads();
  }

  // ---- expvals <Z_j> and channel-sum reduction
  float acc[NQ];
#pragma unroll
  for (int j = 0; j < NQ; ++j) acc[j] = 0.f;
#pragma unroll
  for (int r = 0; r < 8; ++r) {
    int i = lane + (r << 6);
    float2 a = st[wv][i];
    float pr = a.x * a.x + a.y * a.y;
#pragma unroll
    for (int j = 0; j < NQ; ++j)
      acc[j] += ((i >> (8 - j)) & 1) ? -pr : pr;
  }
#pragma unroll
  for (int j = 0; j < NQ; ++j) {
    float v = acc[j];
    for (int m = 1; m < 64; m <<= 1) v += __shfl_xor(v, m, 64);
    if (lane == 0) red[wv][j] = v;
  }
  __syncthreads();
  if (tid < NQ) {
    float s = 0.f;
#pragma unroll
    for (int c = 0; c < CCH; ++c) s += red[c][tid];
    out[blk * NQ + tid] = s;   // raw reshape (Ho,Wo,9) -> flat
  }
}

// ---------------- host: replicate numpy legacy RandomState(42) stream ----------------
namespace {
struct MT {
  uint32_t key[624];
  int pos;
  void seed(uint32_t s) {
    for (int i = 0; i < 624; ++i) {
      key[i] = s;
      s = 1812433253u * (s ^ (s >> 30)) + (uint32_t)i + 1u;
    }
    pos = 624;
  }
  uint32_t next32() {
    if (pos == 624) {
      for (int i = 0; i < 624; ++i) {
        uint32_t y = (key[i] & 0x80000000u) | (key[(i + 1) % 624] & 0x7fffffffu);
        key[i] = key[(i + 397) % 624] ^ (y >> 1) ^ ((y & 1u) ? 0x9908b0dfu : 0u);
      }
      pos = 0;
    }
    uint32_t y = key[pos++];
    y ^= y >> 11;
    y ^= (y << 7)  & 0x9d2c5680u;
    y ^= (y << 15) & 0xefc60000u;
    y ^= y >> 18;
    return y;
  }
  double rnd() {                      // rk_double
    uint32_t a = next32() >> 5, b = next32() >> 6;
    return (a * 67108864.0 + b) / 9007199254740992.0;
  }
  uint32_t bounded32(uint32_t rng) {  // uniform on [0, rng], masked rejection, 32-bit draws
    if (rng == 0) return 0;
    uint32_t mask = rng;
    mask |= mask >> 1;  mask |= mask >> 2;  mask |= mask >> 4;
    mask |= mask >> 8;  mask |= mask >> 16;
    uint32_t v;
    do { v = next32() & mask; } while (v > rng);
    return v;
  }
};
} // namespace

extern "C" void kernel_launch(void* const* d_in, const int* in_sizes, int n_in,
                              void* d_out, int out_size, void* d_ws, size_t ws_size,
                              hipStream_t stream)
{
  const float* x = (const float*)d_in[0];   // (1,8,128,128) f32
  const float* w = (const float*)d_in[1];   // (2,9) f32
  float* out = (float*)d_out;               // 9*126*126 f32

  // Replicate pennylane RandomLayers structure generation (seed 42, static).
  OpList ol;
  ol.n = 0;
  MT mt;
  mt.seed(42u);
  for (int l = 0; l < 2; ++l) {
    int i = 0;
    while (i < NQ) {
      if (mt.rnd() > 0.3) {
        int g  = (int)mt.bounded32(2);   // randint(3)
        int wq = (int)mt.bounded32(8);   // randint(9)
        if (ol.n < MAXOPS)
          ol.ops[ol.n++] = Op{(uint8_t)g, (uint8_t)wq, 0, (uint8_t)(l * NQ + i)};
        ++i;
      } else {
        int arr[NQ];
        for (int t = 0; t < NQ; ++t) arr[t] = t;
        for (int k = NQ - 1; k >= 1; --k) {       // Fisher-Yates (numpy shuffle)
          int j = (int)mt.bounded32((uint32_t)k);
          int tmp = arr[k]; arr[k] = arr[j]; arr[j] = tmp;
        }
        if (ol.n < MAXOPS)
          ol.ops[ol.n++] = Op{3, (uint8_t)arr[0], (uint8_t)arr[1], 0};
      }
    }
  }

  quanv_kernel<<<HO * WO, 512, 0, stream>>>(x, w, out, ol);
}

// Round 2
// 273.163 us; speedup vs baseline: 2.1478x; 2.1478x over previous
//
#include <hip/hip_runtime.h>
#include <stdint.h>

#define NQ    9
#define HIMG  128
#define WIMG  128
#define HO    126
#define WO    126
#define CCH   8
#define MAXOPS 64

struct Op { int type, a, b, widx; };     // 0=RX 1=RY 2=RZ 3=CNOT(a=ctrl,b=tgt)
struct OpList { int n; Op ops[MAXOPS]; };

// ---------- constexpr numpy legacy RandomState(42) (verified bit-exact in R1) ----------
struct MTc {
  uint32_t key[624] {};
  int pos = 624;
  constexpr void seed(uint32_t s) {
    for (int i = 0; i < 624; ++i) {
      key[i] = s;
      s = 1812433253u * (s ^ (s >> 30)) + (uint32_t)i + 1u;
    }
    pos = 624;
  }
  constexpr uint32_t next32() {
    if (pos == 624) {
      for (int i = 0; i < 624; ++i) {
        uint32_t y = (key[i] & 0x80000000u) | (key[(i + 1) % 624] & 0x7fffffffu);
        key[i] = key[(i + 397) % 624] ^ (y >> 1) ^ ((y & 1u) ? 0x9908b0dfu : 0u);
      }
      pos = 0;
    }
    uint32_t y = key[pos++];
    y ^= y >> 11;
    y ^= (y << 7)  & 0x9d2c5680u;
    y ^= (y << 15) & 0xefc60000u;
    y ^= y >> 18;
    return y;
  }
  constexpr double rnd() {
    uint32_t a = next32() >> 5, b = next32() >> 6;
    return (a * 67108864.0 + b) / 9007199254740992.0;
  }
  constexpr uint32_t bounded32(uint32_t rng) {
    if (rng == 0) return 0;
    uint32_t mask = rng;
    mask |= mask >> 1;  mask |= mask >> 2;  mask |= mask >> 4;
    mask |= mask >> 8;  mask |= mask >> 16;
    uint32_t v = next32() & mask;
    while (v > rng) v = next32() & mask;
    return v;
  }
};

constexpr OpList build_ops() {
  OpList ol {};
  ol.n = 0;
  MTc mt {};
  mt.seed(42u);
  for (int l = 0; l < 2; ++l) {
    int i = 0;
    while (i < NQ) {
      if (mt.rnd() > 0.3) {
        int g  = (int)mt.bounded32(2);
        int wq = (int)mt.bounded32(8);
        if (ol.n < MAXOPS) { ol.ops[ol.n] = Op{g, wq, 0, l * NQ + i}; ol.n++; }
        ++i;
      } else {
        int arr[NQ] {};
        for (int t = 0; t < NQ; ++t) arr[t] = t;
        for (int k = NQ - 1; k >= 1; --k) {
          int j = (int)mt.bounded32((uint32_t)k);
          int tmp = arr[k]; arr[k] = arr[j]; arr[j] = tmp;
        }
        if (ol.n < MAXOPS) { ol.ops[ol.n] = Op{3, arr[0], arr[1], 0}; ol.n++; }
      }
    }
  }
  return ol;
}

constexpr OpList kOps = build_ops();
constexpr int KN = kOps.n;

// ---------- fully-unrolled circuit: state = 8 complex amplitudes/lane in VGPRs ----------
// global index i = lane + 64*r : lane bit p (0..5) = wire 8-p ; r bit rb (0..2) = wire 2-rb
template<int K>
__device__ __forceinline__ void apply_ops(float (&sr)[8], float (&si)[8],
                                          const float* __restrict__ wc,
                                          const float* __restrict__ wsn,
                                          int lane)
{
  if constexpr (K < KN) {
    constexpr Op op = kOps.ops[K];
    if constexpr (op.type == 3) {
      constexpr int pc = 8 - op.a, pt = 8 - op.b;
      if constexpr (pc >= 6 && pt >= 6) {
        // both in register bits: static register permutation (free)
        constexpr int crb = pc - 6, trb = pt - 6;
#pragma unroll
        for (int r = 0; r < 8; ++r)
          if (((r >> crb) & 1) == 1 && ((r >> trb) & 1) == 0) {
            int r1 = r | (1 << trb);
            float t;
            t = sr[r]; sr[r] = sr[r1]; sr[r1] = t;
            t = si[r]; si[r] = si[r1]; si[r1] = t;
          }
      } else if constexpr (pc >= 6 && pt <= 5) {
        // control in reg bit, target in lane bit: full cross-lane swap of 4 regs
        constexpr int crb = pc - 6;
#pragma unroll
        for (int r = 0; r < 8; ++r)
          if ((r >> crb) & 1) {
            sr[r] = __shfl_xor(sr[r], 1 << pt, 64);
            si[r] = __shfl_xor(si[r], 1 << pt, 64);
          }
      } else if constexpr (pc <= 5 && pt >= 6) {
        // control in lane bit, target in reg bit: predicated register swap (no shuffle)
        constexpr int trb = pt - 6;
        const bool f = (lane >> pc) & 1;
#pragma unroll
        for (int r = 0; r < 8; ++r)
          if (((r >> trb) & 1) == 0) {
            int r1 = r | (1 << trb);
            float a = sr[r], b = sr[r1];
            sr[r] = f ? b : a;  sr[r1] = f ? a : b;
            a = si[r]; b = si[r1];
            si[r] = f ? b : a;  si[r1] = f ? a : b;
          }
      } else {
        // both lane bits: shuffle + predicated adopt
        const bool f = (lane >> pc) & 1;
#pragma unroll
        for (int r = 0; r < 8; ++r) {
          float orr = __shfl_xor(sr[r], 1 << pt, 64);
          float oii = __shfl_xor(si[r], 1 << pt, 64);
          sr[r] = f ? orr : sr[r];
          si[r] = f ? oii : si[r];
        }
      }
    } else {
      const float c = wc[op.widx], s = wsn[op.widx];
      constexpr int p = 8 - op.a;
      if constexpr (op.type == 2) {
        // RZ diagonal: amp *= exp(-+ i*theta/2); no exchange ever
        if constexpr (p >= 6) {
          constexpr int rb = p - 6;
#pragma unroll
          for (int r = 0; r < 8; ++r) {
            float sg = ((r >> rb) & 1) ? -s : s;
            float nx = c * sr[r] + sg * si[r];
            float ny = c * si[r] - sg * sr[r];
            sr[r] = nx; si[r] = ny;
          }
        } else {
          const float sg = ((lane >> p) & 1) ? -s : s;
#pragma unroll
          for (int r = 0; r < 8; ++r) {
            float nx = c * sr[r] + sg * si[r];
            float ny = c * si[r] - sg * sr[r];
            sr[r] = nx; si[r] = ny;
          }
        }
      } else if constexpr (p >= 6) {
        // RX/RY on register-bit wire: static pair arithmetic
        constexpr int rb = p - 6;
#pragma unroll
        for (int r0 = 0; r0 < 8; ++r0)
          if (((r0 >> rb) & 1) == 0) {
            int r1 = r0 | (1 << rb);
            if constexpr (op.type == 0) {  // RX
              float n0x = c * sr[r0] + s * si[r1];
              float n0y = c * si[r0] - s * sr[r1];
              float n1x = c * sr[r1] + s * si[r0];
              float n1y = c * si[r1] - s * sr[r0];
              sr[r0] = n0x; si[r0] = n0y; sr[r1] = n1x; si[r1] = n1y;
            } else {                        // RY
              float n0x = c * sr[r0] - s * sr[r1];
              float n0y = c * si[r0] - s * si[r1];
              float n1x = c * sr[r1] + s * sr[r0];
              float n1y = c * si[r1] + s * si[r0];
              sr[r0] = n0x; si[r0] = n0y; sr[r1] = n1x; si[r1] = n1y;
            }
          }
      } else {
        // RX/RY on lane-bit wire: shuffle partner, side-resolved update
        if constexpr (op.type == 0) {      // RX: new = c*m + s*(i? ) — side-independent form
#pragma unroll
          for (int r = 0; r < 8; ++r) {
            float ox = __shfl_xor(sr[r], 1 << p, 64);
            float oy = __shfl_xor(si[r], 1 << p, 64);
            sr[r] = c * sr[r] + s * oy;
            si[r] = c * si[r] - s * ox;
          }
        } else {                            // RY
          const float sg = ((lane >> p) & 1) ? s : -s;
#pragma unroll
          for (int r = 0; r < 8; ++r) {
            float ox = __shfl_xor(sr[r], 1 << p, 64);
            float oy = __shfl_xor(si[r], 1 << p, 64);
            sr[r] = c * sr[r] + sg * ox;
            si[r] = c * si[r] + sg * oy;
          }
        }
      }
    }
    apply_ops<K + 1>(sr, si, wc, wsn, lane);
  }
}

__global__ __launch_bounds__(512) void quanv_kernel(
    const float* __restrict__ x, const float* __restrict__ w,
    float* __restrict__ out)
{
  __shared__ float wc[2 * NQ], wsn[2 * NQ];
  __shared__ float red[CCH][NQ];

  const int tid  = threadIdx.x;
  const int lane = tid & 63;
  const int wv   = tid >> 6;          // channel 0..7
  const int blk  = blockIdx.x;        // site = ho*WO + wo
  const int ho   = blk / WO;
  const int wo   = blk - ho * WO;

  if (tid < 2 * NQ) {
    float t = w[tid] * 0.5f;
    sincosf(t, &wsn[tid], &wc[tid]);
  }

  // ---- patch angles: lanes 0..8 compute sincos(pi*x/2), broadcast to wave
  float myc = 1.f, mys = 0.f;
  if (lane < NQ) {
    const float* xp = x + wv * (HIMG * WIMG) + ho * WIMG + wo;
    float v = xp[(lane / 3) * WIMG + (lane % 3)];
    sincosf(1.5707963267948966f * v, &mys, &myc);
  }
  float cs[NQ], sn[NQ];
#pragma unroll
  for (int m = 0; m < NQ; ++m) {
    cs[m] = __shfl(myc, m, 64);
    sn[m] = __shfl(mys, m, 64);
  }

  // ---- initial product state into registers
  float P = 1.f;
#pragma unroll
  for (int p = 0; p < 6; ++p)
    P *= ((lane >> p) & 1) ? sn[8 - p] : cs[8 - p];
  float sr[8], si[8];
#pragma unroll
  for (int r = 0; r < 8; ++r) {
    float g = P;
    g *= ((r     ) & 1) ? sn[2] : cs[2];
    g *= ((r >> 1) & 1) ? sn[1] : cs[1];
    g *= ((r >> 2) & 1) ? sn[0] : cs[0];
    sr[r] = g;
    si[r] = 0.f;
  }

  __syncthreads();          // weights trig ready

  // ---- fully unrolled static circuit
  apply_ops<0>(sr, si, wc, wsn, lane);

  // ---- readout: probs and <Z_j>
  float pr[8], prtot = 0.f;
#pragma unroll
  for (int r = 0; r < 8; ++r) {
    pr[r] = sr[r] * sr[r] + si[r] * si[r];
    prtot += pr[r];
  }
  // reg-bit wires (j=0,1,2): static-signed sums over r, then plain lane-sum
  float s0 = 0.f, s1 = 0.f, s2 = 0.f;
#pragma unroll
  for (int r = 0; r < 8; ++r) {
    s0 += ((r >> 2) & 1) ? -pr[r] : pr[r];   // wire 0 (bit 8 -> rb 2)
    s1 += ((r >> 1) & 1) ? -pr[r] : pr[r];   // wire 1
    s2 += ((r     ) & 1) ? -pr[r] : pr[r];   // wire 2
  }
#pragma unroll
  for (int m = 0; m < 6; ++m) {
    s0 += __shfl_xor(s0, 1 << m, 64);
    s1 += __shfl_xor(s1, 1 << m, 64);
    s2 += __shfl_xor(s2, 1 << m, 64);
  }
  // lane-bit wires (j=3..8): one Walsh-Hadamard butterfly on prtot gives all six
  float v = prtot;
#pragma unroll
  for (int m = 0; m < 6; ++m) {
    float o = __shfl_xor(v, 1 << m, 64);
    v = ((lane >> m) & 1) ? (o - v) : (v + o);
  }
  if (lane == 0) { red[wv][0] = s0; red[wv][1] = s1; red[wv][2] = s2; }
  if (lane != 0 && (lane & (lane - 1)) == 0) {   // lanes 1,2,4,8,16,32
    int pj = __ffs(lane) - 1;                    // bit position 0..5
    red[wv][8 - pj] = v;                         // wire j = 8 - pj
  }
  __syncthreads();

  if (tid < NQ) {
    float s = 0.f;
#pragma unroll
    for (int c = 0; c < CCH; ++c) s += red[c][tid];
    out[blk * NQ + tid] = s;
  }
}

extern "C" void kernel_launch(void* const* d_in, const int* in_sizes, int n_in,
                              void* d_out, int out_size, void* d_ws, size_t ws_size,
                              hipStream_t stream)
{
  const float* x = (const float*)d_in[0];   // (1,8,128,128) f32
  const float* w = (const float*)d_in[1];   // (2,9) f32
  float* out = (float*)d_out;               // (9*126*126) f32

  quanv_kernel<<<HO * WO, 512, 0, stream>>>(x, w, out);
}

// Round 3
// 113.028 us; speedup vs baseline: 5.1908x; 2.4168x over previous
//
#include <hip/hip_runtime.h>
#include <stdint.h>

#define NQ    9
#define HIMG  128
#define WIMG  128
#define HO    126
#define WO    126
#define CCH   8
#define NPIX  (CCH * HIMG * WIMG)
#define MAXRAW 64

struct Op { int type, a, b, widx; };     // 0=RX 1=RY 2=RZ 3=CNOT(a=ctrl,b=tgt)
struct OpList { int n; Op ops[MAXRAW]; };

// ---------- constexpr numpy legacy RandomState(42) (bit-exact, verified R1/R2) ----------
struct MTc {
  uint32_t key[624] {};
  int pos = 624;
  constexpr void seed(uint32_t s) {
    for (int i = 0; i < 624; ++i) {
      key[i] = s;
      s = 1812433253u * (s ^ (s >> 30)) + (uint32_t)i + 1u;
    }
    pos = 624;
  }
  constexpr uint32_t next32() {
    if (pos == 624) {
      for (int i = 0; i < 624; ++i) {
        uint32_t y = (key[i] & 0x80000000u) | (key[(i + 1) % 624] & 0x7fffffffu);
        key[i] = key[(i + 397) % 624] ^ (y >> 1) ^ ((y & 1u) ? 0x9908b0dfu : 0u);
      }
      pos = 0;
    }
    uint32_t y = key[pos++];
    y ^= y >> 11;
    y ^= (y << 7)  & 0x9d2c5680u;
    y ^= (y << 15) & 0xefc60000u;
    y ^= y >> 18;
    return y;
  }
  constexpr double rnd() {
    uint32_t a = next32() >> 5, b = next32() >> 6;
    return (a * 67108864.0 + b) / 9007199254740992.0;
  }
  constexpr uint32_t bounded32(uint32_t rng) {
    if (rng == 0) return 0;
    uint32_t mask = rng;
    mask |= mask >> 1;  mask |= mask >> 2;  mask |= mask >> 4;
    mask |= mask >> 8;  mask |= mask >> 16;
    uint32_t v = next32() & mask;
    while (v > rng) v = next32() & mask;
    return v;
  }
};

constexpr OpList build_ops() {
  OpList ol {};
  ol.n = 0;
  MTc mt {};
  mt.seed(42u);
  for (int l = 0; l < 2; ++l) {
    int i = 0;
    while (i < NQ) {
      if (mt.rnd() > 0.3) {
        int g  = (int)mt.bounded32(2);
        int wq = (int)mt.bounded32(8);
        if (ol.n < MAXRAW) { ol.ops[ol.n] = Op{g, wq, 0, l * NQ + i}; ol.n++; }
        ++i;
      } else {
        int arr[NQ] {};
        for (int t = 0; t < NQ; ++t) arr[t] = t;
        for (int k = NQ - 1; k >= 1; --k) {
          int j = (int)mt.bounded32((uint32_t)k);
          int tmp = arr[k]; arr[k] = arr[j]; arr[j] = tmp;
        }
        if (ol.n < MAXRAW) { ol.ops[ol.n] = Op{3, arr[0], arr[1], 0}; ol.n++; }
      }
    }
  }
  return ol;
}

// ---------- constexpr circuit compiler: fold-into-init, fuse 1q runs, drop diag tails ----------
struct FSpec { int n; int g[24]; int widx[24]; };
struct CGate { int kind; int wire; int c; int t; int fidx; };  // kind 0=gen1q 1=diag1q 2=cnot
struct Circuit {
  int ng; CGate gates[64];
  int nf; FSpec fs[32];
  FSpec initfs[NQ];
  bool hasinit[NQ];
};

constexpr void fappend(FSpec& f, int g, int wi) { f.g[f.n] = g; f.widx[f.n] = wi; f.n = f.n + 1; }

constexpr void flushw(Circuit& C, FSpec* pend, bool* pdiag, int w) {
  if (pend[w].n > 0) {
    C.fs[C.nf] = pend[w];
    CGate gg {};
    gg.kind = pdiag[w] ? 1 : 0;
    gg.wire = w;
    gg.fidx = C.nf;
    C.gates[C.ng] = gg;
    C.nf = C.nf + 1;
    C.ng = C.ng + 1;
    pend[w] = FSpec{};
    pdiag[w] = true;
  }
}

constexpr Circuit build_circuit() {
  Circuit C {};
  OpList raw = build_ops();
  int firstC[NQ] {};
  for (int w = 0; w < NQ; ++w) firstC[w] = 1 << 30;
  for (int k = 0; k < raw.n; ++k)
    if (raw.ops[k].type == 3) {
      if (k < firstC[raw.ops[k].a]) firstC[raw.ops[k].a] = k;
      if (k < firstC[raw.ops[k].b]) firstC[raw.ops[k].b] = k;
    }
  FSpec pend[NQ] {};
  bool pdiag[NQ] {};
  for (int w = 0; w < NQ; ++w) pdiag[w] = true;
  for (int k = 0; k < raw.n; ++k) {
    Op op = raw.ops[k];
    if (op.type < 3) {
      if (k < firstC[op.a]) {                 // pre-first-CNOT: fold into init
        fappend(C.initfs[op.a], op.type, op.widx);
        C.hasinit[op.a] = true;
      } else {
        fappend(pend[op.a], op.type, op.widx);
        if (op.type != 2) pdiag[op.a] = false;
      }
    } else {
      flushw(C, pend, pdiag, op.b);           // target: always flush
      if (!pdiag[op.a]) flushw(C, pend, pdiag, op.a);  // control: diag commutes past
      CGate gg {};
      gg.kind = 2; gg.c = op.a; gg.t = op.b;
      C.gates[C.ng] = gg;
      C.ng = C.ng + 1;
    }
  }
  for (int w = 0; w < NQ; ++w)                // tails: drop pure-diagonal
    if (pend[w].n > 0 && !pdiag[w]) flushw(C, pend, pdiag, w);
  return C;
}

constexpr Circuit kC = build_circuit();

// ---------- constexpr wire->bit assignment search (3 reg-bit wires of 9) ----------
constexpr long circuit_cost(int m) {
  long c = 0;
  for (int i = 0; i < kC.ng; ++i) {
    CGate g = kC.gates[i];
    if (g.kind == 0)      c += ((m >> g.wire) & 1) ? 64 : 100;
    else if (g.kind == 1) c += 48;
    else {
      bool cr = (m >> g.c) & 1, tr = (m >> g.t) & 1;
      c += (cr && tr) ? 8 : (cr ? 24 : (tr ? 16 : 48));
    }
  }
  return c;
}
constexpr int best_mask() {
  long best = (long)1 << 60;
  int bm = 7;
  for (int m = 0; m < 512; ++m) {
    int pc = 0;
    for (int w = 0; w < NQ; ++w) pc += (m >> w) & 1;
    if (pc != 3) continue;
    long c = circuit_cost(m);
    if (c < best) { best = c; bm = m; }
  }
  return bm;
}
struct Perm { int pos[NQ]; bool isreg[NQ]; int laneWire[6]; int regWire[3]; };
constexpr Perm make_perm(int mask) {
  Perm P {};
  int lp = 0, rp = 0;
  for (int w = 0; w < NQ; ++w) {
    if ((mask >> w) & 1) { P.isreg[w] = true;  P.pos[w] = rp; P.regWire[rp] = w; ++rp; }
    else                 { P.isreg[w] = false; P.pos[w] = lp; P.laneWire[lp] = w; ++lp; }
  }
  return P;
}
constexpr Perm kP = make_perm(best_mask());
constexpr int NFT = kC.nf + NQ;   // fused gate matrices + per-wire init matrices

constexpr FSpec get_spec(int F) {
  return F < kC.nf ? kC.fs[F] : kC.initfs[F - kC.nf];
}

// ---------- prep kernel: fused 2x2 matrices from weights (one thread per matrix) ----------
template<int F, int I>
__device__ __forceinline__ void spec_step(float (&m)[8], const float* __restrict__ w) {
  if constexpr (I < get_spec(F).n) {
    constexpr FSpec sp = get_spec(F);
    constexpr int g = sp.g[I];
    float th = 0.5f * w[sp.widx[I]];
    float sh, ch;
    __sincosf(th, &sh, &ch);
    float r0, r1, r2, r3, r4, r5, r6, r7;
    if constexpr (g == 0)      { r0 = ch; r1 = 0.f; r2 = 0.f; r3 = -sh; r4 = 0.f; r5 = -sh; r6 = ch; r7 = 0.f; }
    else if constexpr (g == 1) { r0 = ch; r1 = 0.f; r2 = -sh; r3 = 0.f; r4 = sh;  r5 = 0.f; r6 = ch; r7 = 0.f; }
    else                       { r0 = ch; r1 = -sh; r2 = 0.f; r3 = 0.f; r4 = 0.f; r5 = 0.f; r6 = ch; r7 = sh;  }
    float n0 = r0*m[0] - r1*m[1] + r2*m[4] - r3*m[5];
    float n1 = r0*m[1] + r1*m[0] + r2*m[5] + r3*m[4];
    float n2 = r0*m[2] - r1*m[3] + r2*m[6] - r3*m[7];
    float n3 = r0*m[3] + r1*m[2] + r2*m[7] + r3*m[6];
    float n4 = r4*m[0] - r5*m[1] + r6*m[4] - r7*m[5];
    float n5 = r4*m[1] + r5*m[0] + r6*m[5] + r7*m[4];
    float n6 = r4*m[2] - r5*m[3] + r6*m[6] - r7*m[7];
    float n7 = r4*m[3] + r5*m[2] + r6*m[7] + r7*m[6];
    m[0]=n0; m[1]=n1; m[2]=n2; m[3]=n3; m[4]=n4; m[5]=n5; m[6]=n6; m[7]=n7;
    spec_step<F, I + 1>(m, w);
  }
}

template<int F>
__device__ __forceinline__ void prep_rec(int t, const float* __restrict__ w, float* __restrict__ out) {
  if constexpr (F < NFT) {
    if (t == F) {
      float m[8] = {1.f, 0.f, 0.f, 0.f, 0.f, 0.f, 1.f, 0.f};
      spec_step<F, 0>(m, w);
#pragma unroll
      for (int j = 0; j < 8; ++j) out[F * 8 + j] = m[j];
    }
    prep_rec<F + 1>(t, w, out);
  }
}

__global__ void prep_mats(const float* __restrict__ w, float* __restrict__ out) {
  prep_rec<0>(threadIdx.x, w, out);
}

__global__ void prep_table(const float* __restrict__ x, float2* __restrict__ tab) {
  int i = blockIdx.x * blockDim.x + threadIdx.x;
  if (i < NPIX) {
    float s, c;
    __sincosf(1.5707963267948966f * x[i], &s, &c);
    tab[i] = make_float2(c, s);
  }
}

// ---------- main kernel helpers (all gate params compile-time) ----------
template<int K>
__device__ __forceinline__ void apply(float (&sr)[8], float (&si)[8],
                                      const float* __restrict__ gm, int lane) {
  if constexpr (K < kC.ng) {
    constexpr CGate g = kC.gates[K];
    if constexpr (g.kind == 2) {
      constexpr bool cr = kP.isreg[g.c];
      constexpr bool tr = kP.isreg[g.t];
      constexpr int pc = kP.pos[g.c];
      constexpr int pt = kP.pos[g.t];
      if constexpr (cr && tr) {
#pragma unroll
        for (int r = 0; r < 8; ++r)
          if (((r >> pc) & 1) == 1 && ((r >> pt) & 1) == 0) {
            int r1 = r | (1 << pt);
            float t;
            t = sr[r]; sr[r] = sr[r1]; sr[r1] = t;
            t = si[r]; si[r] = si[r1]; si[r1] = t;
          }
      } else if constexpr (cr && !tr) {
#pragma unroll
        for (int r = 0; r < 8; ++r)
          if ((r >> pc) & 1) {
            sr[r] = __shfl_xor(sr[r], 1 << pt, 64);
            si[r] = __shfl_xor(si[r], 1 << pt, 64);
          }
      } else if constexpr (!cr && tr) {
        const bool f = (lane >> pc) & 1;
#pragma unroll
        for (int r = 0; r < 8; ++r)
          if (((r >> pt) & 1) == 0) {
            int r1 = r | (1 << pt);
            float a = sr[r], b = sr[r1];
            sr[r] = f ? b : a;  sr[r1] = f ? a : b;
            a = si[r]; b = si[r1];
            si[r] = f ? b : a;  si[r1] = f ? a : b;
          }
      } else {
        const bool f = (lane >> pc) & 1;
#pragma unroll
        for (int r = 0; r < 8; ++r) {
          float ox = __shfl_xor(sr[r], 1 << pt, 64);
          float oy = __shfl_xor(si[r], 1 << pt, 64);
          sr[r] = f ? ox : sr[r];
          si[r] = f ? oy : si[r];
        }
      }
    } else {
      constexpr bool wr = kP.isreg[g.wire];
      constexpr int p = kP.pos[g.wire];
      const float* m = gm + g.fidx * 8;
      if constexpr (g.kind == 1) {           // diagonal fused gate
        float d0x = m[0], d0y = m[1], d1x = m[6], d1y = m[7];
        if constexpr (wr) {
#pragma unroll
          for (int r = 0; r < 8; ++r) {
            float px = ((r >> p) & 1) ? d1x : d0x;
            float py = ((r >> p) & 1) ? d1y : d0y;
            float nx = px * sr[r] - py * si[r];
            float ny = px * si[r] + py * sr[r];
            sr[r] = nx; si[r] = ny;
          }
        } else {
          const bool b = (lane >> p) & 1;
          float px = b ? d1x : d0x, py = b ? d1y : d0y;
#pragma unroll
          for (int r = 0; r < 8; ++r) {
            float nx = px * sr[r] - py * si[r];
            float ny = px * si[r] + py * sr[r];
            sr[r] = nx; si[r] = ny;
          }
        }
      } else {                               // generic fused 1q gate
        float u00x = m[0], u00y = m[1], u01x = m[2], u01y = m[3];
        float u10x = m[4], u10y = m[5], u11x = m[6], u11y = m[7];
        if constexpr (wr) {
#pragma unroll
          for (int r0 = 0; r0 < 8; ++r0)
            if (((r0 >> p) & 1) == 0) {
              int r1 = r0 | (1 << p);
              float a0x = sr[r0], a0y = si[r0], a1x = sr[r1], a1y = si[r1];
              sr[r0] = u00x*a0x - u00y*a0y + u01x*a1x - u01y*a1y;
              si[r0] = u00x*a0y + u00y*a0x + u01x*a1y + u01y*a1x;
              sr[r1] = u10x*a0x - u10y*a0y + u11x*a1x - u11y*a1y;
              si[r1] = u10x*a0y + u10y*a0x + u11x*a1y + u11y*a1x;
            }
        } else {
          const bool b = (lane >> p) & 1;
          float uax = b ? u11x : u00x, uay = b ? u11y : u00y;
          float ubx = b ? u10x : u01x, uby = b ? u10y : u01y;
#pragma unroll
          for (int r = 0; r < 8; ++r) {
            float ox = __shfl_xor(sr[r], 1 << p, 64);
            float oy = __shfl_xor(si[r], 1 << p, 64);
            float mx = sr[r], my = si[r];
            sr[r] = uax*mx - uay*my + ubx*ox - uby*oy;
            si[r] = uax*my + uay*mx + ubx*oy + uby*ox;
          }
        }
      }
    }
    apply<K + 1>(sr, si, gm, lane);
  }
}

template<int P>
__device__ __forceinline__ void init_lane_mult(float& Lx, float& Ly,
                                               const float* __restrict__ gm,
                                               const float (&cw)[NQ], const float (&sw)[NQ],
                                               int lane) {
  if constexpr (P < 6) {
    constexpr int w = kP.laneWire[P];
    float ax, ay, bx, by;
    if constexpr (kC.hasinit[w]) {
      const float* M = gm + (kC.nf + w) * 8;
      ax = M[0]*cw[w] + M[2]*sw[w];
      ay = M[1]*cw[w] + M[3]*sw[w];
      bx = M[4]*cw[w] + M[6]*sw[w];
      by = M[5]*cw[w] + M[7]*sw[w];
    } else {
      ax = cw[w]; ay = 0.f; bx = sw[w]; by = 0.f;
    }
    bool s = (lane >> P) & 1;
    float fx = s ? bx : ax, fy = s ? by : ay;
    float nx = Lx * fx - Ly * fy;
    float ny = Lx * fy + Ly * fx;
    Lx = nx; Ly = ny;
    init_lane_mult<P + 1>(Lx, Ly, gm, cw, sw, lane);
  }
}

template<int RB>
__device__ __forceinline__ void init_reg_vec(float (&rax)[3], float (&ray)[3],
                                             float (&rbx)[3], float (&rby)[3],
                                             const float* __restrict__ gm,
                                             const float (&cw)[NQ], const float (&sw)[NQ]) {
  if constexpr (RB < 3) {
    constexpr int w = kP.regWire[RB];
    if constexpr (kC.hasinit[w]) {
      const float* M = gm + (kC.nf + w) * 8;
      rax[RB] = M[0]*cw[w] + M[2]*sw[w];
      ray[RB] = M[1]*cw[w] + M[3]*sw[w];
      rbx[RB] = M[4]*cw[w] + M[6]*sw[w];
      rby[RB] = M[5]*cw[w] + M[7]*sw[w];
    } else {
      rax[RB] = cw[w]; ray[RB] = 0.f; rbx[RB] = sw[w]; rby[RB] = 0.f;
    }
    init_reg_vec<RB + 1>(rax, ray, rbx, rby, gm, cw, sw);
  }
}

template<int RB>
__device__ __forceinline__ void write_reg(float (&red)[CCH][NQ], int wv, int lane,
                                          const float (&sreg)[3]) {
  if constexpr (RB < 3) {
    if (lane == 0) red[wv][kP.regWire[RB]] = sreg[RB];
    write_reg<RB + 1>(red, wv, lane, sreg);
  }
}

template<int P>
__device__ __forceinline__ void write_lane(float (&red)[CCH][NQ], int wv, int lane, float v) {
  if constexpr (P < 6) {
    if (lane == (1 << P)) red[wv][kP.laneWire[P]] = v;
    write_lane<P + 1>(red, wv, lane, v);
  }
}

// ---------- main kernel ----------
template<bool TAB>
__global__ __launch_bounds__(512) void quanv_kernel(
    const float* __restrict__ x, const float2* __restrict__ tab,
    const float* __restrict__ mats, float* __restrict__ out)
{
  __shared__ float gm[NFT * 8];
  __shared__ float red[CCH][NQ];

  const int tid  = threadIdx.x;
  const int lane = tid & 63;
  const int wv   = tid >> 6;          // channel 0..7
  const int blk  = blockIdx.x;        // site = ho*WO + wo
  const int ho   = blk / WO;
  const int wo   = blk - ho * WO;

  if (tid < NFT * 8) gm[tid] = mats[tid];

  // pixel trig (cos(pi x/2), sin(pi x/2)) per wire
  float cw[NQ], sw[NQ];
  if constexpr (TAB) {
    const float2* tp = tab + wv * (HIMG * WIMG) + ho * WIMG + wo;
#pragma unroll
    for (int mq = 0; mq < NQ; ++mq) {
      float2 v = tp[(mq / 3) * WIMG + (mq % 3)];
      cw[mq] = v.x; sw[mq] = v.y;
    }
  } else {
    float myc = 1.f, mys = 0.f;
    if (lane < NQ) {
      const float* xp = x + wv * (HIMG * WIMG) + ho * WIMG + wo;
      float v = xp[(lane / 3) * WIMG + (lane % 3)];
      __sincosf(1.5707963267948966f * v, &mys, &myc);
    }
#pragma unroll
    for (int mq = 0; mq < NQ; ++mq) {
      cw[mq] = __shfl(myc, mq, 64);
      sw[mq] = __shfl(mys, mq, 64);
    }
  }

  __syncthreads();   // gm ready

  // ---- initial product state (encoding RY + folded pre-CNOT rotations)
  float Lx = 1.f, Ly = 0.f;
  init_lane_mult<0>(Lx, Ly, gm, cw, sw, lane);
  float rax[3], ray[3], rbx[3], rby[3];
  init_reg_vec<0>(rax, ray, rbx, rby, gm, cw, sw);

  float sr[8], si[8];
#pragma unroll
  for (int r = 0; r < 8; ++r) {
    float Tx = Lx, Ty = Ly;
#pragma unroll
    for (int rb = 0; rb < 3; ++rb) {
      float fx = ((r >> rb) & 1) ? rbx[rb] : rax[rb];
      float fy = ((r >> rb) & 1) ? rby[rb] : ray[rb];
      float nx = Tx * fx - Ty * fy;
      float ny = Tx * fy + Ty * fx;
      Tx = nx; Ty = ny;
    }
    sr[r] = Tx; si[r] = Ty;
  }

  // ---- compiled circuit body
  apply<0>(sr, si, gm, lane);

  // ---- readout
  float pr[8], prtot = 0.f;
#pragma unroll
  for (int r = 0; r < 8; ++r) {
    pr[r] = sr[r] * sr[r] + si[r] * si[r];
    prtot += pr[r];
  }
  float sreg[3];
#pragma unroll
  for (int rb = 0; rb < 3; ++rb) {
    float s = 0.f;
#pragma unroll
    for (int r = 0; r < 8; ++r) s += ((r >> rb) & 1) ? -pr[r] : pr[r];
#pragma unroll
    for (int mm = 0; mm < 6; ++mm) s += __shfl_xor(s, 1 << mm, 64);
    sreg[rb] = s;
  }
  float v = prtot;
#pragma unroll
  for (int mm = 0; mm < 6; ++mm) {
    float o = __shfl_xor(v, 1 << mm, 64);
    v = ((lane >> mm) & 1) ? (o - v) : (v + o);
  }
  write_reg<0>(red, wv, lane, sreg);
  write_lane<0>(red, wv, lane, v);
  __syncthreads();

  if (tid < NQ) {
    float s = 0.f;
#pragma unroll
    for (int c = 0; c < CCH; ++c) s += red[c][tid];
    out[blk * NQ + tid] = s;
  }
}

extern "C" void kernel_launch(void* const* d_in, const int* in_sizes, int n_in,
                              void* d_out, int out_size, void* d_ws, size_t ws_size,
                              hipStream_t stream)
{
  const float* x = (const float*)d_in[0];   // (1,8,128,128) f32
  const float* w = (const float*)d_in[1];   // (2,9) f32
  float* out = (float*)d_out;               // (9*126*126) f32

  float* mats = (float*)d_ws;               // NFT*8 floats at offset 0
  const size_t tab_off = 4096;
  bool useTab = ws_size >= tab_off + (size_t)NPIX * sizeof(float2);

  prep_mats<<<1, 64, 0, stream>>>(w, mats);
  if (useTab) {
    float2* tab = (float2*)((char*)d_ws + tab_off);
    prep_table<<<(NPIX + 511) / 512, 512, 0, stream>>>(x, tab);
    quanv_kernel<true><<<HO * WO, 512, 0, stream>>>(x, tab, mats, out);
  } else {
    quanv_kernel<false><<<HO * WO, 512, 0, stream>>>(x, nullptr, mats, out);
  }
}

// Round 4
// 98.686 us; speedup vs baseline: 5.9452x; 1.1453x over previous
//
#include <hip/hip_runtime.h>
#include <stdint.h>

#define NQ    9
#define HIMG  128
#define WIMG  128
#define HO    126
#define WO    126
#define CCH   8
#define NPIX  (CCH * HIMG * WIMG)
#define MAXRAW 64
#define USE_PK 1

typedef float f2 __attribute__((ext_vector_type(2)));

struct Op { int type, a, b, widx; };     // 0=RX 1=RY 2=RZ 3=CNOT(a=ctrl,b=tgt)
struct OpList { int n; Op ops[MAXRAW]; };

// ---------- constexpr numpy legacy RandomState(42) (bit-exact, verified R1-R3) ----------
struct MTc {
  uint32_t key[624] {};
  int pos = 624;
  constexpr void seed(uint32_t s) {
    for (int i = 0; i < 624; ++i) {
      key[i] = s;
      s = 1812433253u * (s ^ (s >> 30)) + (uint32_t)i + 1u;
    }
    pos = 624;
  }
  constexpr uint32_t next32() {
    if (pos == 624) {
      for (int i = 0; i < 624; ++i) {
        uint32_t y = (key[i] & 0x80000000u) | (key[(i + 1) % 624] & 0x7fffffffu);
        key[i] = key[(i + 397) % 624] ^ (y >> 1) ^ ((y & 1u) ? 0x9908b0dfu : 0u);
      }
      pos = 0;
    }
    uint32_t y = key[pos++];
    y ^= y >> 11;
    y ^= (y << 7)  & 0x9d2c5680u;
    y ^= (y << 15) & 0xefc60000u;
    y ^= y >> 18;
    return y;
  }
  constexpr double rnd() {
    uint32_t a = next32() >> 5, b = next32() >> 6;
    return (a * 67108864.0 + b) / 9007199254740992.0;
  }
  constexpr uint32_t bounded32(uint32_t rng) {
    if (rng == 0) return 0;
    uint32_t mask = rng;
    mask |= mask >> 1;  mask |= mask >> 2;  mask |= mask >> 4;
    mask |= mask >> 8;  mask |= mask >> 16;
    uint32_t v = next32() & mask;
    while (v > rng) v = next32() & mask;
    return v;
  }
};

constexpr OpList build_ops() {
  OpList ol {};
  ol.n = 0;
  MTc mt {};
  mt.seed(42u);
  for (int l = 0; l < 2; ++l) {
    int i = 0;
    while (i < NQ) {
      if (mt.rnd() > 0.3) {
        int g  = (int)mt.bounded32(2);
        int wq = (int)mt.bounded32(8);
        if (ol.n < MAXRAW) { ol.ops[ol.n] = Op{g, wq, 0, l * NQ + i}; ol.n++; }
        ++i;
      } else {
        int arr[NQ] {};
        for (int t = 0; t < NQ; ++t) arr[t] = t;
        for (int k = NQ - 1; k >= 1; --k) {
          int j = (int)mt.bounded32((uint32_t)k);
          int tmp = arr[k]; arr[k] = arr[j]; arr[j] = tmp;
        }
        if (ol.n < MAXRAW) { ol.ops[ol.n] = Op{3, arr[0], arr[1], 0}; ol.n++; }
      }
    }
  }
  return ol;
}

// ---------- pass 1: fold-into-init, fuse 1q runs, drop diagonal tails (wire space) ----------
struct FSpec { int n; int g[24]; int widx[24]; };
struct CGate { int kind; int wire; int c; int t; int fidx; };  // 0=gen1q 1=diag1q 2=cnot
struct Circuit {
  int ng; CGate gates[64];
  int nf; FSpec fs[32];
  FSpec initfs[NQ];
  bool hasinit[NQ];
};

constexpr void fappend(FSpec& f, int g, int wi) { f.g[f.n] = g; f.widx[f.n] = wi; f.n = f.n + 1; }

constexpr void flushw(Circuit& C, FSpec* pend, bool* pdiag, int w) {
  if (pend[w].n > 0) {
    C.fs[C.nf] = pend[w];
    CGate gg {};
    gg.kind = pdiag[w] ? 1 : 0;
    gg.wire = w;
    gg.fidx = C.nf;
    C.gates[C.ng] = gg;
    C.nf = C.nf + 1;
    C.ng = C.ng + 1;
    pend[w] = FSpec{};
    pdiag[w] = true;
  }
}

constexpr Circuit build_circuit() {
  Circuit C {};
  OpList raw = build_ops();
  int firstC[NQ] {};
  for (int w = 0; w < NQ; ++w) firstC[w] = 1 << 30;
  for (int k = 0; k < raw.n; ++k)
    if (raw.ops[k].type == 3) {
      if (k < firstC[raw.ops[k].a]) firstC[raw.ops[k].a] = k;
      if (k < firstC[raw.ops[k].b]) firstC[raw.ops[k].b] = k;
    }
  FSpec pend[NQ] {};
  bool pdiag[NQ] {};
  for (int w = 0; w < NQ; ++w) pdiag[w] = true;
  for (int k = 0; k < raw.n; ++k) {
    Op op = raw.ops[k];
    if (op.type < 3) {
      if (k < firstC[op.a]) {
        fappend(C.initfs[op.a], op.type, op.widx);
        C.hasinit[op.a] = true;
      } else {
        fappend(pend[op.a], op.type, op.widx);
        if (op.type != 2) pdiag[op.a] = false;
      }
    } else {
      flushw(C, pend, pdiag, op.b);
      if (!pdiag[op.a]) flushw(C, pend, pdiag, op.a);
      CGate gg {};
      gg.kind = 2; gg.c = op.a; gg.t = op.b;
      C.gates[C.ng] = gg;
      C.ng = C.ng + 1;
    }
  }
  for (int w = 0; w < NQ; ++w)
    if (pend[w].n > 0 && !pdiag[w]) flushw(C, pend, pdiag, w);
  return C;
}

constexpr Circuit kC = build_circuit();

// ---------- pass 2: defer ALL CNOTs through GF(2)-linear tracking ----------
// stored state b relates to physical by psi = P_L b, P_L|i> = |L i>.
// CNOT(c,t): L.row[t] ^= L.row[c];  K=L^-1: K[i].bit(c) ^= K[i].bit(t).
// 1q on wire w: pair mask v = K e_w (column w of K), side mask rw = L.row[w].
struct MGate { int kind; int v; int rw; int fidx; };  // kind 0=gen 1=diag
struct MCirc { int ng; MGate g[64]; int outmask[NQ]; };

constexpr MCirc build_masked() {
  MCirc M {};
  int Lrow[NQ] {}, Krow[NQ] {};
  for (int i = 0; i < NQ; ++i) { Lrow[i] = 1 << i; Krow[i] = 1 << i; }
  for (int k = 0; k < kC.ng; ++k) {
    CGate g = kC.gates[k];
    if (g.kind == 2) {
      Lrow[g.t] ^= Lrow[g.c];
      for (int i = 0; i < NQ; ++i)
        if ((Krow[i] >> g.t) & 1) Krow[i] ^= (1 << g.c);
    } else {
      int v = 0;
      for (int i = 0; i < NQ; ++i) v |= ((Krow[i] >> g.wire) & 1) << i;
      MGate mg {};
      mg.kind = g.kind; mg.v = v; mg.rw = Lrow[g.wire]; mg.fidx = g.fidx;
      M.g[M.ng] = mg; M.ng = M.ng + 1;
    }
  }
  for (int w = 0; w < NQ; ++w) M.outmask[w] = Lrow[w];
  return M;
}

constexpr MCirc kMC = build_masked();

// ---------- wire->bit assignment (6 lane bits, 3 reg bits) with cost search ----------
struct Perm { int pos[NQ]; bool isreg[NQ]; int laneWire[6]; int regWire[3]; };
constexpr Perm make_perm(int mask) {
  Perm P {};
  int lp = 0, rp = 0;
  for (int w = 0; w < NQ; ++w) {
    if ((mask >> w) & 1) { P.isreg[w] = true;  P.pos[w] = rp; P.regWire[rp] = w; ++rp; }
    else                 { P.isreg[w] = false; P.pos[w] = lp; P.laneWire[lp] = w; ++lp; }
  }
  return P;
}
constexpr int lanep_of(int m, const Perm& P) {
  int r = 0;
  for (int w = 0; w < NQ; ++w)
    if (((m >> w) & 1) && !P.isreg[w]) r |= 1 << P.pos[w];
  return r;
}
constexpr int regp_of(int m, const Perm& P) {
  int r = 0;
  for (int w = 0; w < NQ; ++w)
    if (((m >> w) & 1) && P.isreg[w]) r |= 1 << P.pos[w];
  return r;
}
constexpr long cost_mask(int mask) {
  Perm P = make_perm(mask);
  long c = 0;
  for (int i = 0; i < kMC.ng; ++i) {
    MGate g = kMC.g[i];
    int vl = lanep_of(g.v, P);
    int rl = lanep_of(g.rw, P);
    if (g.kind == 0) c += 32 + (vl ? 16 : 0) + (rl ? 8 : 0);
    else             c += 16 + (rl ? 4 : 0);
  }
  int seen[NQ] {}; int ns = 0;
  for (int w = 0; w < NQ; ++w) {
    int rp = regp_of(kMC.outmask[w], P);
    bool f = false;
    for (int j = 0; j < ns; ++j) if (seen[j] == rp) f = true;
    if (!f) { seen[ns] = rp; ns = ns + 1; }
  }
  c += 8 + (long)ns * 20;
  return c;
}
constexpr int best_mask() {
  long best = (long)1 << 60;
  int bm = 7;
  for (int m = 0; m < 512; ++m) {
    int pc = 0;
    for (int w = 0; w < NQ; ++w) pc += (m >> w) & 1;
    if (pc != 3) continue;
    long c = cost_mask(m);
    if (c < best) { best = c; bm = m; }
  }
  return bm;
}
constexpr Perm kP = make_perm(best_mask());
constexpr int LP(int m) { return lanep_of(m, kP); }
constexpr int RP(int m) { return regp_of(m, kP); }

constexpr int NFT = kC.nf + NQ;   // fused matrices + per-wire init matrices

// readout groups by reg-part of outmask
struct RG { int ng; int rmask[NQ]; int cnt[NQ]; int wire[NQ][NQ]; };
constexpr RG build_groups() {
  RG G {};
  for (int w = 0; w < NQ; ++w) {
    int rp = RP(kMC.outmask[w]);
    int gi = -1;
    for (int j = 0; j < G.ng; ++j) if (G.rmask[j] == rp) gi = j;
    if (gi < 0) { gi = G.ng; G.rmask[gi] = rp; G.cnt[gi] = 0; G.ng = G.ng + 1; }
    G.wire[gi][G.cnt[gi]] = w;
    G.cnt[gi] = G.cnt[gi] + 1;
  }
  return G;
}
constexpr RG kRG = build_groups();

// ---------- packed-fp32 complex helpers ----------
// complex z=(re,im) in one f2 (VGPR pair). cmul: z = u*a ; cfma: z = u*a + c
#if USE_PK
__device__ __forceinline__ f2 cmul(f2 u, f2 a) {
  f2 t;
  // t = (u.x*a.x, u.x*a.y)
  asm("v_pk_mul_f32 %0, %1, %2 op_sel:[0,0] op_sel_hi:[0,1]"
      : "=v"(t) : "v"(u), "v"(a));
  // lo: -u.y*a.y + t.lo ; hi: u.y*a.x + t.hi
  asm("v_pk_fma_f32 %0, %1, %2, %0 op_sel:[1,1,0] op_sel_hi:[1,0,1] neg_lo:[1,0,0] neg_hi:[0,0,0]"
      : "+v"(t) : "v"(u), "v"(a));
  return t;
}
__device__ __forceinline__ f2 cfma(f2 u, f2 a, f2 c) {
  f2 t;
  asm("v_pk_fma_f32 %0, %1, %2, %3 op_sel:[0,0,0] op_sel_hi:[0,1,1]"
      : "=v"(t) : "v"(u), "v"(a), "v"(c));
  asm("v_pk_fma_f32 %0, %1, %2, %0 op_sel:[1,1,0] op_sel_hi:[1,0,1] neg_lo:[1,0,0] neg_hi:[0,0,0]"
      : "+v"(t) : "v"(u), "v"(a));
  return t;
}
// (cs.x*m.x, cs.x*m.y)
__device__ __forceinline__ f2 slo_mul(f2 cs, f2 m) {
  f2 t;
  asm("v_pk_mul_f32 %0, %1, %2 op_sel:[0,0] op_sel_hi:[0,1]"
      : "=v"(t) : "v"(cs), "v"(m));
  return t;
}
// c + cs.y*m
__device__ __forceinline__ f2 shi_fma(f2 cs, f2 m, f2 c) {
  f2 t;
  asm("v_pk_fma_f32 %0, %1, %2, %3 op_sel:[1,0,0] op_sel_hi:[1,1,1]"
      : "=v"(t) : "v"(cs), "v"(m), "v"(c));
  return t;
}
#else
__device__ __forceinline__ f2 cmul(f2 u, f2 a) {
  f2 r; r.x = u.x * a.x - u.y * a.y; r.y = u.x * a.y + u.y * a.x; return r;
}
__device__ __forceinline__ f2 cfma(f2 u, f2 a, f2 c) {
  f2 r; r.x = c.x + u.x * a.x - u.y * a.y; r.y = c.y + u.x * a.y + u.y * a.x; return r;
}
__device__ __forceinline__ f2 slo_mul(f2 cs, f2 m) { f2 r; r.x = cs.x * m.x; r.y = cs.x * m.y; return r; }
__device__ __forceinline__ f2 shi_fma(f2 cs, f2 m, f2 c) { f2 r; r.x = c.x + cs.y * m.x; r.y = c.y + cs.y * m.y; return r; }
#endif

__device__ __forceinline__ f2 shflx(f2 v, int m) {
  f2 r;
  r.x = __shfl_xor(v.x, m, 64);
  r.y = __shfl_xor(v.y, m, 64);
  return r;
}

// ---------- prep kernel: fused 2x2 matrices from weights ----------
constexpr FSpec get_spec(int F) {
  return F < kC.nf ? kC.fs[F] : kC.initfs[F - kC.nf];
}

template<int F, int I>
__device__ __forceinline__ void spec_step(float (&m)[8], const float* __restrict__ w) {
  if constexpr (I < get_spec(F).n) {
    constexpr FSpec sp = get_spec(F);
    constexpr int g = sp.g[I];
    float th = 0.5f * w[sp.widx[I]];
    float sh, ch;
    __sincosf(th, &sh, &ch);
    float r0, r1, r2, r3, r4, r5, r6, r7;
    if constexpr (g == 0)      { r0 = ch; r1 = 0.f; r2 = 0.f; r3 = -sh; r4 = 0.f; r5 = -sh; r6 = ch; r7 = 0.f; }
    else if constexpr (g == 1) { r0 = ch; r1 = 0.f; r2 = -sh; r3 = 0.f; r4 = sh;  r5 = 0.f; r6 = ch; r7 = 0.f; }
    else                       { r0 = ch; r1 = -sh; r2 = 0.f; r3 = 0.f; r4 = 0.f; r5 = 0.f; r6 = ch; r7 = sh;  }
    float n0 = r0*m[0] - r1*m[1] + r2*m[4] - r3*m[5];
    float n1 = r0*m[1] + r1*m[0] + r2*m[5] + r3*m[4];
    float n2 = r0*m[2] - r1*m[3] + r2*m[6] - r3*m[7];
    float n3 = r0*m[3] + r1*m[2] + r2*m[7] + r3*m[6];
    float n4 = r4*m[0] - r5*m[1] + r6*m[4] - r7*m[5];
    float n5 = r4*m[1] + r5*m[0] + r6*m[5] + r7*m[4];
    float n6 = r4*m[2] - r5*m[3] + r6*m[6] - r7*m[7];
    float n7 = r4*m[3] + r5*m[2] + r6*m[7] + r7*m[6];
    m[0]=n0; m[1]=n1; m[2]=n2; m[3]=n3; m[4]=n4; m[5]=n5; m[6]=n6; m[7]=n7;
    spec_step<F, I + 1>(m, w);
  }
}

template<int F>
__device__ __forceinline__ void prep_rec(int t, const float* __restrict__ w, float* __restrict__ out) {
  if constexpr (F < NFT) {
    if (t == F) {
      float m[8] = {1.f, 0.f, 0.f, 0.f, 0.f, 0.f, 1.f, 0.f};
      spec_step<F, 0>(m, w);
#pragma unroll
      for (int j = 0; j < 8; ++j) out[F * 8 + j] = m[j];
    }
    prep_rec<F + 1>(t, w, out);
  }
}

__global__ void prep_mats(const float* __restrict__ w, float* __restrict__ out) {
  prep_rec<0>(threadIdx.x, w, out);
}

__global__ void prep_table(const float* __restrict__ x, f2* __restrict__ tab) {
  int i = blockIdx.x * blockDim.x + threadIdx.x;
  if (i < NPIX) {
    float s, c;
    __sincosf(1.5707963267948966f * x[i], &s, &c);
    f2 v; v.x = c; v.y = s;
    tab[i] = v;
  }
}

// ---------- compiled masked-gate circuit ----------
template<int K>
__device__ __forceinline__ void apply(f2 (&st)[8], const f2* __restrict__ gm, int lane) {
  if constexpr (K < kMC.ng) {
    constexpr MGate g = kMC.g[K];
    constexpr int vl = LP(g.v), vr = RP(g.v);
    constexpr int rl = LP(g.rw), rr = RP(g.rw);
    const f2* m = gm + g.fidx * 4;   // (u00, u01, u10, u11)
    if constexpr (g.kind == 1) {
      // diagonal gate: multiplier d_s, s = parity(rw & i)
      f2 d0 = m[0], d1 = m[3];
      f2 dA, dB;
      if constexpr (rl != 0) {
        const bool pl = __builtin_popcount(lane & rl) & 1;
        dA = pl ? d1 : d0;
        dB = pl ? d0 : d1;
      } else { dA = d0; dB = d1; }
#pragma unroll
      for (int r = 0; r < 8; ++r)
        st[r] = cmul(((__builtin_popcount(r & rr) & 1) ? dB : dA), st[r]);
    } else {
      // general 1q gate on pairs i <-> i^v ; side s(i) = parity(rw & i)
      // out(i) = ua_s * mine + ub_s * partner; ua_0=u00 ub_0=u01 ua_1=u11 ub_1=u10
      f2 u00 = m[0], u01 = m[1], u10 = m[2], u11 = m[3];
      f2 uaA, ubA, uaB, ubB;   // A: static(reg)-side 0, B: static-side 1
      if constexpr (rl != 0) {
        const bool pl = __builtin_popcount(lane & rl) & 1;
        uaA = pl ? u11 : u00; ubA = pl ? u10 : u01;
        uaB = pl ? u00 : u11; ubB = pl ? u01 : u10;
      } else {
        uaA = u00; ubA = u01; uaB = u11; ubB = u10;
      }
      if constexpr (vr == 0) {
        // pure cross-lane pairing, mine-centric
#pragma unroll
        for (int r = 0; r < 8; ++r) {
          f2 o = shflx(st[r], vl);
          const bool sb = __builtin_popcount(r & rr) & 1;   // compile-time folded
          f2 ua = sb ? uaB : uaA;
          f2 ub = sb ? ubB : ubA;
          st[r] = cfma(ub, o, cmul(ua, st[r]));
        }
      } else {
        constexpr int low = vr & (-vr);
#pragma unroll
        for (int r = 0; r < 8; ++r)
          if ((r & low) == 0) {
            const int r2 = r ^ vr;
            f2 a = st[r], b = st[r2];
            f2 oa, ob;
            if constexpr (vl != 0) { oa = shflx(b, vl); ob = shflx(a, vl); }
            else                   { oa = b;            ob = a;            }
            const bool s1 = __builtin_popcount(r  & rr) & 1;
            const bool s2 = __builtin_popcount(r2 & rr) & 1;
            f2 ua1 = s1 ? uaB : uaA, ub1 = s1 ? ubB : ubA;
            f2 ua2 = s2 ? uaB : uaA, ub2 = s2 ? ubB : ubA;
            st[r]  = cfma(ub1, oa, cmul(ua1, a));
            st[r2] = cfma(ub2, ob, cmul(ua2, b));
          }
      }
    }
    apply<K + 1>(st, gm, lane);
  }
}

// ---------- init product state ----------
template<int P>
__device__ __forceinline__ void lane_fold(f2& L, const f2* __restrict__ gm,
                                          const f2 (&csw)[NQ], int lane) {
  if constexpr (P < 6) {
    constexpr int w = kP.laneWire[P];
    f2 Aw, Bw;
    if constexpr (kC.hasinit[w]) {
      const f2* M = gm + (kC.nf + w) * 4;
      f2 cs = csw[w];
      Aw = shi_fma(cs, M[1], slo_mul(cs, M[0]));
      Bw = shi_fma(cs, M[3], slo_mul(cs, M[2]));
    } else {
      Aw.x = csw[w].x; Aw.y = 0.f;
      Bw.x = csw[w].y; Bw.y = 0.f;
    }
    f2 f = ((lane >> P) & 1) ? Bw : Aw;
    if constexpr (P == 0) L = f;
    else L = cmul(L, f);
    lane_fold<P + 1>(L, gm, csw, lane);
  }
}

template<int RB>
__device__ __forceinline__ void reg_fac(f2 (&ra)[3], f2 (&rb)[3], const f2* __restrict__ gm,
                                        const f2 (&csw)[NQ]) {
  if constexpr (RB < 3) {
    constexpr int w = kP.regWire[RB];
    if constexpr (kC.hasinit[w]) {
      const f2* M = gm + (kC.nf + w) * 4;
      f2 cs = csw[w];
      ra[RB] = shi_fma(cs, M[1], slo_mul(cs, M[0]));
      rb[RB] = shi_fma(cs, M[3], slo_mul(cs, M[2]));
    } else {
      ra[RB].x = csw[w].x; ra[RB].y = 0.f;
      rb[RB].x = csw[w].y; rb[RB].y = 0.f;
    }
    reg_fac<RB + 1>(ra, rb, gm, csw);
  }
}

// ---------- readout ----------
template<int GI, int WI>
__device__ __forceinline__ void emit_wires(float (&red)[CCH][NQ], int wv, int lane, float val) {
  if constexpr (WI < kRG.cnt[GI]) {
    constexpr int w = kRG.wire[GI][WI];
    constexpr int lml = LP(kMC.outmask[w]);
    if (lane == lml) red[wv][w] = val;
    emit_wires<GI, WI + 1>(red, wv, lane, val);
  }
}

template<int GI>
__device__ __forceinline__ void readout_groups(const f2 (&sq)[8], float (&red)[CCH][NQ],
                                               int wv, int lane) {
  if constexpr (GI < kRG.ng) {
    constexpr int rm = kRG.rmask[GI];
    f2 acc = sq[0];
#pragma unroll
    for (int r = 1; r < 8; ++r)
      acc = (__builtin_popcount(r & rm) & 1) ? acc - sq[r] : acc + sq[r];
    float h = acc.x + acc.y;
#pragma unroll
    for (int mm = 0; mm < 6; ++mm) {
      float o = __shfl_xor(h, 1 << mm, 64);
      h = ((lane >> mm) & 1) ? (o - h) : (h + o);
    }
    emit_wires<GI, 0>(red, wv, lane, h);
    readout_groups<GI + 1>(sq, red, wv, lane);
  }
}

// ---------- main kernel ----------
template<bool TAB>
__global__ __launch_bounds__(512) void quanv_kernel(
    const float* __restrict__ x, const f2* __restrict__ tab,
    const float* __restrict__ mats, float* __restrict__ out)
{
  __shared__ f2 gm[NFT * 4];
  __shared__ float red[CCH][NQ];

  const int tid  = threadIdx.x;
  const int lane = tid & 63;
  const int wv   = tid >> 6;          // channel 0..7
  const int blk  = blockIdx.x;        // site = ho*WO + wo
  const int ho   = blk / WO;
  const int wo   = blk - ho * WO;

  if (tid < NFT * 4) gm[tid] = ((const f2*)mats)[tid];

  // (cos, sin) of pi*x/2 per wire
  f2 csw[NQ];
  if constexpr (TAB) {
    const f2* tp = tab + wv * (HIMG * WIMG) + ho * WIMG + wo;
#pragma unroll
    for (int mq = 0; mq < NQ; ++mq)
      csw[mq] = tp[(mq / 3) * WIMG + (mq % 3)];
  } else {
    float myc = 1.f, mys = 0.f;
    if (lane < NQ) {
      const float* xp = x + wv * (HIMG * WIMG) + ho * WIMG + wo;
      float v = xp[(lane / 3) * WIMG + (lane % 3)];
      __sincosf(1.5707963267948966f * v, &mys, &myc);
    }
#pragma unroll
    for (int mq = 0; mq < NQ; ++mq) {
      csw[mq].x = __shfl(myc, mq, 64);
      csw[mq].y = __shfl(mys, mq, 64);
    }
  }

  __syncthreads();   // gm ready

  // ---- initial product state (encoding RY + folded pre-CNOT rotations), shared tree
  f2 L;
  lane_fold<0>(L, gm, csw, lane);
  f2 ra[3], rb[3];
  reg_fac<0>(ra, rb, gm, csw);

  f2 st[8];
  {
    f2 La = cmul(L, ra[0]), Lb = cmul(L, rb[0]);
    f2 T0 = cmul(La, ra[1]), T1 = cmul(Lb, ra[1]);
    f2 T2 = cmul(La, rb[1]), T3 = cmul(Lb, rb[1]);
    st[0] = cmul(T0, ra[2]); st[1] = cmul(T1, ra[2]);
    st[2] = cmul(T2, ra[2]); st[3] = cmul(T3, ra[2]);
    st[4] = cmul(T0, rb[2]); st[5] = cmul(T1, rb[2]);
    st[6] = cmul(T2, rb[2]); st[7] = cmul(T3, rb[2]);
  }

  // ---- compiled circuit (CNOT-free, masked gates)
  apply<0>(st, gm, lane);

  // ---- readout
  f2 sq[8];
#pragma unroll
  for (int r = 0; r < 8; ++r) sq[r] = st[r] * st[r];
  readout_groups<0>(sq, red, wv, lane);
  __syncthreads();

  if (tid < NQ) {
    float s = 0.f;
#pragma unroll
    for (int c = 0; c < CCH; ++c) s += red[c][tid];
    out[blk * NQ + tid] = s;
  }
}

extern "C" void kernel_launch(void* const* d_in, const int* in_sizes, int n_in,
                              void* d_out, int out_size, void* d_ws, size_t ws_size,
                              hipStream_t stream)
{
  const float* x = (const float*)d_in[0];   // (1,8,128,128) f32
  const float* w = (const float*)d_in[1];   // (2,9) f32
  float* out = (float*)d_out;               // (9*126*126) f32

  float* mats = (float*)d_ws;               // NFT*8 floats at offset 0
  const size_t tab_off = 4096;
  bool useTab = ws_size >= tab_off + (size_t)NPIX * sizeof(f2);

  prep_mats<<<1, 64, 0, stream>>>(w, mats);
  if (useTab) {
    f2* tab = (f2*)((char*)d_ws + tab_off);
    prep_table<<<(NPIX + 511) / 512, 512, 0, stream>>>(x, tab);
    quanv_kernel<true><<<HO * WO, 512, 0, stream>>>(x, tab, mats, out);
  } else {
    quanv_kernel<false><<<HO * WO, 512, 0, stream>>>(x, nullptr, mats, out);
  }
}

// Round 5
// 90.303 us; speedup vs baseline: 6.4971x; 1.0928x over previous
//
#include <hip/hip_runtime.h>
#include <stdint.h>

#define NQ    9
#define HIMG  128
#define WIMG  128
#define HO    126
#define WO    126
#define CCH   8
#define NPIX  (CCH * HIMG * WIMG)
#define MAXRAW 64
#define USE_PK 1

typedef float f2 __attribute__((ext_vector_type(2)));

struct Op { int type, a, b, widx; };     // 0=RX 1=RY 2=RZ 3=CNOT(a=ctrl,b=tgt)
struct OpList { int n; Op ops[MAXRAW]; };

// ---------- constexpr numpy legacy RandomState(42) (bit-exact, verified R1-R4) ----------
struct MTc {
  uint32_t key[624] {};
  int pos = 624;
  constexpr void seed(uint32_t s) {
    for (int i = 0; i < 624; ++i) {
      key[i] = s;
      s = 1812433253u * (s ^ (s >> 30)) + (uint32_t)i + 1u;
    }
    pos = 624;
  }
  constexpr uint32_t next32() {
    if (pos == 624) {
      for (int i = 0; i < 624; ++i) {
        uint32_t y = (key[i] & 0x80000000u) | (key[(i + 1) % 624] & 0x7fffffffu);
        key[i] = key[(i + 397) % 624] ^ (y >> 1) ^ ((y & 1u) ? 0x9908b0dfu : 0u);
      }
      pos = 0;
    }
    uint32_t y = key[pos++];
    y ^= y >> 11;
    y ^= (y << 7)  & 0x9d2c5680u;
    y ^= (y << 15) & 0xefc60000u;
    y ^= y >> 18;
    return y;
  }
  constexpr double rnd() {
    uint32_t a = next32() >> 5, b = next32() >> 6;
    return (a * 67108864.0 + b) / 9007199254740992.0;
  }
  constexpr uint32_t bounded32(uint32_t rng) {
    if (rng == 0) return 0;
    uint32_t mask = rng;
    mask |= mask >> 1;  mask |= mask >> 2;  mask |= mask >> 4;
    mask |= mask >> 8;  mask |= mask >> 16;
    uint32_t v = next32() & mask;
    while (v > rng) v = next32() & mask;
    return v;
  }
};

constexpr OpList build_ops() {
  OpList ol {};
  ol.n = 0;
  MTc mt {};
  mt.seed(42u);
  for (int l = 0; l < 2; ++l) {
    int i = 0;
    while (i < NQ) {
      if (mt.rnd() > 0.3) {
        int g  = (int)mt.bounded32(2);
        int wq = (int)mt.bounded32(8);
        if (ol.n < MAXRAW) { ol.ops[ol.n] = Op{g, wq, 0, l * NQ + i}; ol.n++; }
        ++i;
      } else {
        int arr[NQ] {};
        for (int t = 0; t < NQ; ++t) arr[t] = t;
        for (int k = NQ - 1; k >= 1; --k) {
          int j = (int)mt.bounded32((uint32_t)k);
          int tmp = arr[k]; arr[k] = arr[j]; arr[j] = tmp;
        }
        if (ol.n < MAXRAW) { ol.ops[ol.n] = Op{3, arr[0], arr[1], 0}; ol.n++; }
      }
    }
  }
  return ol;
}

// ---------- pass 1: fold-into-init, fuse 1q runs, drop diagonal tails (wire space) ----------
struct FSpec { int n; int g[24]; int widx[24]; };
// cls: 0=GENERAL 1=REAL(all-RY) 2=XTYPE(all-RX); diagonal runs use kind=1
struct CGate { int kind; int wire; int c; int t; int fidx; int cls; };
struct Circuit {
  int ng; CGate gates[64];
  int nf; FSpec fs[32];
  FSpec initfs[NQ];
  bool hasinit[NQ];
};

constexpr void fappend(FSpec& f, int g, int wi) { f.g[f.n] = g; f.widx[f.n] = wi; f.n = f.n + 1; }

constexpr int spec_cls(const FSpec& f) {
  bool rx = false, ry = false, rz = false;
  for (int i = 0; i < f.n; ++i) {
    if (f.g[i] == 0) rx = true;
    else if (f.g[i] == 1) ry = true;
    else rz = true;
  }
  if (ry && !rx && !rz) return 1;
  if (rx && !ry && !rz) return 2;
  return 0;
}

constexpr void flushw(Circuit& C, FSpec* pend, bool* pdiag, int w) {
  if (pend[w].n > 0) {
    C.fs[C.nf] = pend[w];
    CGate gg {};
    gg.kind = pdiag[w] ? 1 : 0;
    gg.wire = w;
    gg.fidx = C.nf;
    gg.cls  = pdiag[w] ? 0 : spec_cls(pend[w]);
    C.gates[C.ng] = gg;
    C.nf = C.nf + 1;
    C.ng = C.ng + 1;
    pend[w] = FSpec{};
    pdiag[w] = true;
  }
}

constexpr Circuit build_circuit() {
  Circuit C {};
  OpList raw = build_ops();
  int firstC[NQ] {};
  for (int w = 0; w < NQ; ++w) firstC[w] = 1 << 30;
  for (int k = 0; k < raw.n; ++k)
    if (raw.ops[k].type == 3) {
      if (k < firstC[raw.ops[k].a]) firstC[raw.ops[k].a] = k;
      if (k < firstC[raw.ops[k].b]) firstC[raw.ops[k].b] = k;
    }
  FSpec pend[NQ] {};
  bool pdiag[NQ] {};
  for (int w = 0; w < NQ; ++w) pdiag[w] = true;
  for (int k = 0; k < raw.n; ++k) {
    Op op = raw.ops[k];
    if (op.type < 3) {
      if (k < firstC[op.a]) {
        fappend(C.initfs[op.a], op.type, op.widx);
        C.hasinit[op.a] = true;
      } else {
        fappend(pend[op.a], op.type, op.widx);
        if (op.type != 2) pdiag[op.a] = false;
      }
    } else {
      flushw(C, pend, pdiag, op.b);
      if (!pdiag[op.a]) flushw(C, pend, pdiag, op.a);
      CGate gg {};
      gg.kind = 2; gg.c = op.a; gg.t = op.b;
      C.gates[C.ng] = gg;
      C.ng = C.ng + 1;
    }
  }
  for (int w = 0; w < NQ; ++w)
    if (pend[w].n > 0 && !pdiag[w]) flushw(C, pend, pdiag, w);
  return C;
}

constexpr Circuit kC = build_circuit();

// ---------- pass 2: defer ALL CNOTs through GF(2)-linear tracking ----------
struct MGate { int kind; int v; int rw; int fidx; int cls; };
struct MCirc { int ng; MGate g[64]; int outmask[NQ]; };

constexpr MCirc build_masked() {
  MCirc M {};
  int Lrow[NQ] {}, Krow[NQ] {};
  for (int i = 0; i < NQ; ++i) { Lrow[i] = 1 << i; Krow[i] = 1 << i; }
  for (int k = 0; k < kC.ng; ++k) {
    CGate g = kC.gates[k];
    if (g.kind == 2) {
      Lrow[g.t] ^= Lrow[g.c];
      for (int i = 0; i < NQ; ++i)
        if ((Krow[i] >> g.t) & 1) Krow[i] ^= (1 << g.c);
    } else {
      int v = 0;
      for (int i = 0; i < NQ; ++i) v |= ((Krow[i] >> g.wire) & 1) << i;
      MGate mg {};
      mg.kind = g.kind; mg.v = v; mg.rw = Lrow[g.wire]; mg.fidx = g.fidx; mg.cls = g.cls;
      M.g[M.ng] = mg; M.ng = M.ng + 1;
    }
  }
  for (int w = 0; w < NQ; ++w) M.outmask[w] = Lrow[w];
  return M;
}

constexpr MCirc kMC = build_masked();

// ---------- wire->bit assignment (6 lane bits, 3 reg bits) with cost search ----------
struct Perm { int pos[NQ]; bool isreg[NQ]; int laneWire[6]; int regWire[3]; };
constexpr Perm make_perm(int mask) {
  Perm P {};
  int lp = 0, rp = 0;
  for (int w = 0; w < NQ; ++w) {
    if ((mask >> w) & 1) { P.isreg[w] = true;  P.pos[w] = rp; P.regWire[rp] = w; ++rp; }
    else                 { P.isreg[w] = false; P.pos[w] = lp; P.laneWire[lp] = w; ++lp; }
  }
  return P;
}
constexpr int lanep_of(int m, const Perm& P) {
  int r = 0;
  for (int w = 0; w < NQ; ++w)
    if (((m >> w) & 1) && !P.isreg[w]) r |= 1 << P.pos[w];
  return r;
}
constexpr int regp_of(int m, const Perm& P) {
  int r = 0;
  for (int w = 0; w < NQ; ++w)
    if (((m >> w) & 1) && P.isreg[w]) r |= 1 << P.pos[w];
  return r;
}
constexpr long cost_mask(int mask) {
  Perm P = make_perm(mask);
  long c = 0;
  for (int i = 0; i < kMC.ng; ++i) {
    MGate g = kMC.g[i];
    int vl = lanep_of(g.v, P);
    int rl = lanep_of(g.rw, P);
    if (g.kind == 1)      c += 16 + (rl ? 2 : 0);
    else if (g.cls == 1)  c += 16 + (vl ? 8 : 0) + (rl ? 2 : 0);
    else if (g.cls == 2)  c += 16 + (vl ? 8 : 0);
    else                  c += 32 + (vl ? 16 : 0) + (rl ? 4 : 0);
  }
  int seen[NQ] {}; int ns = 0;
  for (int w = 0; w < NQ; ++w) {
    int rp = regp_of(kMC.outmask[w], P);
    bool f = false;
    for (int j = 0; j < ns; ++j) if (seen[j] == rp) f = true;
    if (!f) { seen[ns] = rp; ns = ns + 1; }
  }
  c += 8 + (long)ns * 14;
  return c;
}
constexpr int best_mask() {
  long best = (long)1 << 60;
  int bm = 7;
  for (int m = 0; m < 512; ++m) {
    int pc = 0;
    for (int w = 0; w < NQ; ++w) pc += (m >> w) & 1;
    if (pc != 3) continue;
    long c = cost_mask(m);
    if (c < best) { best = c; bm = m; }
  }
  return bm;
}
constexpr Perm kP = make_perm(best_mask());
constexpr int LP(int m) { return lanep_of(m, kP); }
constexpr int RP(int m) { return regp_of(m, kP); }

constexpr int NFT = kC.nf + NQ;   // fused matrices + per-wire init matrices

// readout groups by reg-part of outmask
struct RG { int ng; int rmask[NQ]; int cnt[NQ]; int wire[NQ][NQ]; };
constexpr RG build_groups() {
  RG G {};
  for (int w = 0; w < NQ; ++w) {
    int rp = RP(kMC.outmask[w]);
    int gi = -1;
    for (int j = 0; j < G.ng; ++j) if (G.rmask[j] == rp) gi = j;
    if (gi < 0) { gi = G.ng; G.rmask[gi] = rp; G.cnt[gi] = 0; G.ng = G.ng + 1; }
    G.wire[gi][G.cnt[gi]] = w;
    G.cnt[gi] = G.cnt[gi] + 1;
  }
  return G;
}
constexpr RG kRG = build_groups();

// ---------- packed-fp32 complex helpers ----------
#if USE_PK
__device__ __forceinline__ f2 cmul(f2 u, f2 a) {
  f2 t;
  asm("v_pk_mul_f32 %0, %1, %2 op_sel:[0,0] op_sel_hi:[0,1]"
      : "=v"(t) : "v"(u), "v"(a));
  asm("v_pk_fma_f32 %0, %1, %2, %0 op_sel:[1,1,0] op_sel_hi:[1,0,1] neg_lo:[1,0,0] neg_hi:[0,0,0]"
      : "+v"(t) : "v"(u), "v"(a));
  return t;
}
__device__ __forceinline__ f2 cfma(f2 u, f2 a, f2 c) {
  f2 t;
  asm("v_pk_fma_f32 %0, %1, %2, %3 op_sel:[0,0,0] op_sel_hi:[0,1,1]"
      : "=v"(t) : "v"(u), "v"(a), "v"(c));
  asm("v_pk_fma_f32 %0, %1, %2, %0 op_sel:[1,1,0] op_sel_hi:[1,0,1] neg_lo:[1,0,0] neg_hi:[0,0,0]"
      : "+v"(t) : "v"(u), "v"(a));
  return t;
}
// (cs.x*m.x, cs.x*m.y)
__device__ __forceinline__ f2 slo_mul(f2 cs, f2 m) {
  f2 t;
  asm("v_pk_mul_f32 %0, %1, %2 op_sel:[0,0] op_sel_hi:[0,1]"
      : "=v"(t) : "v"(cs), "v"(m));
  return t;
}
// c + cs.y*m
__device__ __forceinline__ f2 shi_fma(f2 cs, f2 m, f2 c) {
  f2 t;
  asm("v_pk_fma_f32 %0, %1, %2, %3 op_sel:[1,0,0] op_sel_hi:[1,1,1]"
      : "=v"(t) : "v"(cs), "v"(m), "v"(c));
  return t;
}
// t + (cs.y*o.y, -cs.y*o.x)   [XTYPE cross term: -i*S applied to o]
__device__ __forceinline__ f2 xt_fma(f2 cs, f2 o, f2 t) {
  asm("v_pk_fma_f32 %0, %1, %2, %0 op_sel:[1,1,0] op_sel_hi:[1,0,1] neg_lo:[0,0,0] neg_hi:[1,0,0]"
      : "+v"(t) : "v"(cs), "v"(o));
  return t;
}
#else
__device__ __forceinline__ f2 cmul(f2 u, f2 a) {
  f2 r; r.x = u.x * a.x - u.y * a.y; r.y = u.x * a.y + u.y * a.x; return r;
}
__device__ __forceinline__ f2 cfma(f2 u, f2 a, f2 c) {
  f2 r; r.x = c.x + u.x * a.x - u.y * a.y; r.y = c.y + u.x * a.y + u.y * a.x; return r;
}
__device__ __forceinline__ f2 slo_mul(f2 cs, f2 m) { f2 r; r.x = cs.x * m.x; r.y = cs.x * m.y; return r; }
__device__ __forceinline__ f2 shi_fma(f2 cs, f2 m, f2 c) { f2 r; r.x = c.x + cs.y * m.x; r.y = c.y + cs.y * m.y; return r; }
__device__ __forceinline__ f2 xt_fma(f2 cs, f2 o, f2 t) { f2 r; r.x = t.x + cs.y * o.y; r.y = t.y - cs.y * o.x; return r; }
#endif

__device__ __forceinline__ f2 shflx(f2 v, int m) {
  f2 r;
  r.x = __shfl_xor(v.x, m, 64);
  r.y = __shfl_xor(v.y, m, 64);
  return r;
}

// ---------- prep kernel: fused 2x2 matrices from weights ----------
constexpr FSpec get_spec(int F) {
  return F < kC.nf ? kC.fs[F] : kC.initfs[F - kC.nf];
}

template<int F, int I>
__device__ __forceinline__ void spec_step(float (&m)[8], const float* __restrict__ w) {
  if constexpr (I < get_spec(F).n) {
    constexpr FSpec sp = get_spec(F);
    constexpr int g = sp.g[I];
    float th = 0.5f * w[sp.widx[I]];
    float sh, ch;
    __sincosf(th, &sh, &ch);
    float r0, r1, r2, r3, r4, r5, r6, r7;
    if constexpr (g == 0)      { r0 = ch; r1 = 0.f; r2 = 0.f; r3 = -sh; r4 = 0.f; r5 = -sh; r6 = ch; r7 = 0.f; }
    else if constexpr (g == 1) { r0 = ch; r1 = 0.f; r2 = -sh; r3 = 0.f; r4 = sh;  r5 = 0.f; r6 = ch; r7 = 0.f; }
    else                       { r0 = ch; r1 = -sh; r2 = 0.f; r3 = 0.f; r4 = 0.f; r5 = 0.f; r6 = ch; r7 = sh;  }
    float n0 = r0*m[0] - r1*m[1] + r2*m[4] - r3*m[5];
    float n1 = r0*m[1] + r1*m[0] + r2*m[5] + r3*m[4];
    float n2 = r0*m[2] - r1*m[3] + r2*m[6] - r3*m[7];
    float n3 = r0*m[3] + r1*m[2] + r2*m[7] + r3*m[6];
    float n4 = r4*m[0] - r5*m[1] + r6*m[4] - r7*m[5];
    float n5 = r4*m[1] + r5*m[0] + r6*m[5] + r7*m[4];
    float n6 = r4*m[2] - r5*m[3] + r6*m[6] - r7*m[7];
    float n7 = r4*m[3] + r5*m[2] + r6*m[7] + r7*m[6];
    m[0]=n0; m[1]=n1; m[2]=n2; m[3]=n3; m[4]=n4; m[5]=n5; m[6]=n6; m[7]=n7;
    spec_step<F, I + 1>(m, w);
  }
}

template<int F>
__device__ __forceinline__ void prep_rec(int t, const float* __restrict__ w, float* __restrict__ out) {
  if constexpr (F < NFT) {
    if (t == F) {
      float m[8] = {1.f, 0.f, 0.f, 0.f, 0.f, 0.f, 1.f, 0.f};
      spec_step<F, 0>(m, w);
#pragma unroll
      for (int j = 0; j < 8; ++j) out[F * 8 + j] = m[j];
    }
    prep_rec<F + 1>(t, w, out);
  }
}

__global__ void prep_mats(const float* __restrict__ w, float* __restrict__ out) {
  prep_rec<0>(threadIdx.x, w, out);
}

__global__ void prep_table(const float* __restrict__ x, f2* __restrict__ tab) {
  int i = blockIdx.x * blockDim.x + threadIdx.x;
  if (i < NPIX) {
    float s, c;
    __sincosf(1.5707963267948966f * x[i], &s, &c);
    f2 v; v.x = c; v.y = s;
    tab[i] = v;
  }
}

// ---------- compiled masked-gate circuit ----------
template<int K>
__device__ __forceinline__ void apply(f2 (&st)[8], const f2* __restrict__ gm, int lane) {
  if constexpr (K < kMC.ng) {
    constexpr MGate g = kMC.g[K];
    constexpr int vl = LP(g.v), vr = RP(g.v);
    constexpr int rl = LP(g.rw), rr = RP(g.rw);
    const f2* m = gm + g.fidx * 4;   // (u00, u01, u10, u11)
    if constexpr (g.kind == 1) {
      // diagonal gate
      f2 d0 = m[0], d1 = m[3];
      f2 dA, dB;
      if constexpr (rl != 0) {
        const bool pl = __builtin_popcount(lane & rl) & 1;
        dA = pl ? d1 : d0;
        dB = pl ? d0 : d1;
      } else { dA = d0; dB = d1; }
#pragma unroll
      for (int r = 0; r < 8; ++r)
        st[r] = cmul(((__builtin_popcount(r & rr) & 1) ? dB : dA), st[r]);
    } else if constexpr (g.cls == 2) {
      // XTYPE [[C,-iS],[-iS,C]] — symmetric, side-independent: out = C*m + (S*o.y, -S*o.x)
      f2 cs; cs.x = m[0].x; cs.y = -m[1].y;
      if constexpr (vr == 0) {
#pragma unroll
        for (int r = 0; r < 8; ++r) {
          f2 o = shflx(st[r], vl);
          st[r] = xt_fma(cs, o, slo_mul(cs, st[r]));
        }
      } else {
        constexpr int low = vr & (-vr);
#pragma unroll
        for (int r = 0; r < 8; ++r)
          if ((r & low) == 0) {
            const int r2 = r ^ vr;
            f2 a = st[r], b = st[r2];
            f2 oa, ob;
            if constexpr (vl != 0) { oa = shflx(b, vl); ob = shflx(a, vl); }
            else                   { oa = b;            ob = a;            }
            st[r]  = xt_fma(cs, oa, slo_mul(cs, a));
            st[r2] = xt_fma(cs, ob, slo_mul(cs, b));
          }
      }
    } else if constexpr (g.cls == 1) {
      // REAL [[C,-S],[S,C]]: out(side) = C*m + (side ? S : -S)*o
      const float C = m[0].x, S = m[2].x;
      float q0y;
      if constexpr (rl != 0) {
        const bool pl = __builtin_popcount(lane & rl) & 1;
        q0y = pl ? S : -S;      // side(r)=pl^pr ; pr=0 -> S_eff = pl? S : -S
      } else {
        q0y = -S;
      }
      f2 q0; q0.x = C; q0.y = q0y;
      f2 q1; q1.x = C; q1.y = -q0y;
      if constexpr (vr == 0) {
#pragma unroll
        for (int r = 0; r < 8; ++r) {
          f2 o = shflx(st[r], vl);
          const bool pr = __builtin_popcount(r & rr) & 1;
          f2 q = pr ? q1 : q0;
          st[r] = shi_fma(q, o, slo_mul(q, st[r]));
        }
      } else {
        constexpr int low = vr & (-vr);
#pragma unroll
        for (int r = 0; r < 8; ++r)
          if ((r & low) == 0) {
            const int r2 = r ^ vr;
            f2 a = st[r], b = st[r2];
            f2 oa, ob;
            if constexpr (vl != 0) { oa = shflx(b, vl); ob = shflx(a, vl); }
            else                   { oa = b;            ob = a;            }
            const bool s1 = __builtin_popcount(r  & rr) & 1;
            const bool s2 = __builtin_popcount(r2 & rr) & 1;
            f2 qa = s1 ? q1 : q0;
            f2 qb = s2 ? q1 : q0;
            st[r]  = shi_fma(qa, oa, slo_mul(qa, a));
            st[r2] = shi_fma(qb, ob, slo_mul(qb, b));
          }
      }
    } else {
      // GENERAL SU(2): u11=conj(u00), u10=-conj(u01) -> 2 scalar selects + negations
      f2 u00 = m[0], u01 = m[1];
      float a_y, b_x;
      if constexpr (rl != 0) {
        const bool pl = __builtin_popcount(lane & rl) & 1;
        a_y = pl ? -u00.y : u00.y;
        b_x = pl ? -u01.x : u01.x;
      } else {
        a_y = u00.y;
        b_x = u01.x;
      }
      f2 uaA; uaA.x = u00.x; uaA.y = a_y;
      f2 ubA; ubA.x = b_x;   ubA.y = u01.y;
      f2 uaB; uaB.x = u00.x; uaB.y = -a_y;
      f2 ubB; ubB.x = -b_x;  ubB.y = u01.y;
      if constexpr (vr == 0) {
#pragma unroll
        for (int r = 0; r < 8; ++r) {
          f2 o = shflx(st[r], vl);
          const bool sb = __builtin_popcount(r & rr) & 1;
          f2 ua = sb ? uaB : uaA;
          f2 ub = sb ? ubB : ubA;
          st[r] = cfma(ub, o, cmul(ua, st[r]));
        }
      } else {
        constexpr int low = vr & (-vr);
#pragma unroll
        for (int r = 0; r < 8; ++r)
          if ((r & low) == 0) {
            const int r2 = r ^ vr;
            f2 a = st[r], b = st[r2];
            f2 oa, ob;
            if constexpr (vl != 0) { oa = shflx(b, vl); ob = shflx(a, vl); }
            else                   { oa = b;            ob = a;            }
            const bool s1 = __builtin_popcount(r  & rr) & 1;
            const bool s2 = __builtin_popcount(r2 & rr) & 1;
            f2 ua1 = s1 ? uaB : uaA, ub1 = s1 ? ubB : ubA;
            f2 ua2 = s2 ? uaB : uaA, ub2 = s2 ? ubB : ubA;
            st[r]  = cfma(ub1, oa, cmul(ua1, a));
            st[r2] = cfma(ub2, ob, cmul(ua2, b));
          }
      }
    }
    apply<K + 1>(st, gm, lane);
  }
}

// ---------- init product state ----------
template<int P>
__device__ __forceinline__ void lane_fold(f2& L, const f2* __restrict__ gm,
                                          const f2 (&csw)[NQ], int lane) {
  if constexpr (P < 6) {
    constexpr int w = kP.laneWire[P];
    f2 Aw, Bw;
    if constexpr (kC.hasinit[w]) {
      const f2* M = gm + (kC.nf + w) * 4;
      f2 cs = csw[w];
      Aw = shi_fma(cs, M[1], slo_mul(cs, M[0]));
      Bw = shi_fma(cs, M[3], slo_mul(cs, M[2]));
    } else {
      Aw.x = csw[w].x; Aw.y = 0.f;
      Bw.x = csw[w].y; Bw.y = 0.f;
    }
    f2 f = ((lane >> P) & 1) ? Bw : Aw;
    if constexpr (P == 0) L = f;
    else L = cmul(L, f);
    lane_fold<P + 1>(L, gm, csw, lane);
  }
}

template<int RB>
__device__ __forceinline__ void reg_fac(f2 (&ra)[3], f2 (&rb)[3], const f2* __restrict__ gm,
                                        const f2 (&csw)[NQ]) {
  if constexpr (RB < 3) {
    constexpr int w = kP.regWire[RB];
    if constexpr (kC.hasinit[w]) {
      const f2* M = gm + (kC.nf + w) * 4;
      f2 cs = csw[w];
      ra[RB] = shi_fma(cs, M[1], slo_mul(cs, M[0]));
      rb[RB] = shi_fma(cs, M[3], slo_mul(cs, M[2]));
    } else {
      ra[RB].x = csw[w].x; ra[RB].y = 0.f;
      rb[RB].x = csw[w].y; rb[RB].y = 0.f;
    }
    reg_fac<RB + 1>(ra, rb, gm, csw);
  }
}

// ---------- readout ----------
template<int GI, int WI>
__device__ __forceinline__ void emit_wires(float (&red)[CCH][NQ], int wv, int lane, float val) {
  if constexpr (WI < kRG.cnt[GI]) {
    constexpr int w = kRG.wire[GI][WI];
    constexpr int lml = LP(kMC.outmask[w]);
    if (lane == lml) red[wv][w] = val;
    emit_wires<GI, WI + 1>(red, wv, lane, val);
  }
}

template<int GI>
__device__ __forceinline__ void readout_groups(const f2 (&wht)[8], float (&red)[CCH][NQ],
                                               int wv, int lane) {
  if constexpr (GI < kRG.ng) {
    constexpr int rm = kRG.rmask[GI];
    f2 acc = wht[rm];
    float h = acc.x + acc.y;
#pragma unroll
    for (int mm = 0; mm < 6; ++mm) {
      float o = __shfl_xor(h, 1 << mm, 64);
      h = ((lane >> mm) & 1) ? (o - h) : (h + o);
    }
    emit_wires<GI, 0>(red, wv, lane, h);
    readout_groups<GI + 1>(wht, red, wv, lane);
  }
}

// ---------- main kernel ----------
template<bool TAB>
__global__ __launch_bounds__(512) void quanv_kernel(
    const float* __restrict__ x, const f2* __restrict__ tab,
    const float* __restrict__ mats, float* __restrict__ out)
{
  __shared__ f2 gm[NFT * 4];
  __shared__ float red[CCH][NQ];

  const int tid  = threadIdx.x;
  const int lane = tid & 63;
  const int wv   = tid >> 6;          // channel 0..7
  const int blk  = blockIdx.x;        // site = ho*WO + wo
  const int ho   = blk / WO;
  const int wo   = blk - ho * WO;

  if (tid < NFT * 4) gm[tid] = ((const f2*)mats)[tid];

  // (cos, sin) of pi*x/2 per wire
  f2 csw[NQ];
  if constexpr (TAB) {
    const f2* tp = tab + wv * (HIMG * WIMG) + ho * WIMG + wo;
#pragma unroll
    for (int mq = 0; mq < NQ; ++mq)
      csw[mq] = tp[(mq / 3) * WIMG + (mq % 3)];
  } else {
    float myc = 1.f, mys = 0.f;
    if (lane < NQ) {
      const float* xp = x + wv * (HIMG * WIMG) + ho * WIMG + wo;
      float v = xp[(lane / 3) * WIMG + (lane % 3)];
      __sincosf(1.5707963267948966f * v, &mys, &myc);
    }
#pragma unroll
    for (int mq = 0; mq < NQ; ++mq) {
      csw[mq].x = __shfl(myc, mq, 64);
      csw[mq].y = __shfl(mys, mq, 64);
    }
  }

  __syncthreads();   // gm ready

  // ---- initial product state (encoding RY + folded pre-CNOT rotations)
  f2 L;
  lane_fold<0>(L, gm, csw, lane);
  f2 ra[3], rb[3];
  reg_fac<0>(ra, rb, gm, csw);

  f2 st[8];
  {
    f2 La = cmul(L, ra[0]), Lb = cmul(L, rb[0]);
    f2 T0 = cmul(La, ra[1]), T1 = cmul(Lb, ra[1]);
    f2 T2 = cmul(La, rb[1]), T3 = cmul(Lb, rb[1]);
    st[0] = cmul(T0, ra[2]); st[1] = cmul(T1, ra[2]);
    st[2] = cmul(T2, ra[2]); st[3] = cmul(T3, ra[2]);
    st[4] = cmul(T0, rb[2]); st[5] = cmul(T1, rb[2]);
    st[6] = cmul(T2, rb[2]); st[7] = cmul(T3, rb[2]);
  }

  // ---- compiled circuit (CNOT-free, masked, class-specialized gates)
  apply<0>(st, gm, lane);

  // ---- readout: |amp|^2 then shared 3-level Walsh over reg bits
  f2 wht[8];
#pragma unroll
  for (int r = 0; r < 8; ++r) wht[r] = st[r] * st[r];
#pragma unroll
  for (int b = 1; b < 8; b <<= 1) {
#pragma unroll
    for (int r = 0; r < 8; ++r)
      if ((r & b) == 0) {
        f2 a = wht[r], c = wht[r | b];
        wht[r]     = a + c;
        wht[r | b] = a - c;
      }
  }
  readout_groups<0>(wht, red, wv, lane);
  __syncthreads();

  if (tid < NQ) {
    float s = 0.f;
#pragma unroll
    for (int c = 0; c < CCH; ++c) s += red[c][tid];
    out[blk * NQ + tid] = s;
  }
}

extern "C" void kernel_launch(void* const* d_in, const int* in_sizes, int n_in,
                              void* d_out, int out_size, void* d_ws, size_t ws_size,
                              hipStream_t stream)
{
  const float* x = (const float*)d_in[0];   // (1,8,128,128) f32
  const float* w = (const float*)d_in[1];   // (2,9) f32
  float* out = (float*)d_out;               // (9*126*126) f32

  float* mats = (float*)d_ws;               // NFT*8 floats at offset 0
  const size_t tab_off = 4096;
  bool useTab = ws_size >= tab_off + (size_t)NPIX * sizeof(f2);

  prep_mats<<<1, 64, 0, stream>>>(w, mats);
  if (useTab) {
    f2* tab = (f2*)((char*)d_ws + tab_off);
    prep_table<<<(NPIX + 511) / 512, 512, 0, stream>>>(x, tab);
    quanv_kernel<true><<<HO * WO, 512, 0, stream>>>(x, tab, mats, out);
  } else {
    quanv_kernel<false><<<HO * WO, 512, 0, stream>>>(x, nullptr, mats, out);
  }
}

// Round 6
// 16.176 us; speedup vs baseline: 36.2705x; 5.5826x over previous
//
#include <hip/hip_runtime.h>
#include <stdint.h>

#define NQ     9
#define NW     18
#define HIMG   128
#define WIMG   128
#define HO     126
#define WO     126
#define CCH    8
#define NPIX   (CCH * HIMG * WIMG)
#define NSITES (HO * WO)
#define MAXRAW 64
#define MAXT   4096
#define SPB    32          // sites per block
#define TPB    256         // 32 sites x 8 channels

typedef float f2 __attribute__((ext_vector_type(2)));

struct Op { int type, a, b, widx; };     // 0=RX 1=RY 2=RZ 3=CNOT(a=ctrl,b=tgt)
struct OpList { int n; Op ops[MAXRAW]; };

// ---------- constexpr numpy legacy RandomState(42) (bit-exact, verified R1-R5) ----------
struct MTc {
  uint32_t key[624] {};
  int pos = 624;
  constexpr void seed(uint32_t s) {
    for (int i = 0; i < 624; ++i) {
      key[i] = s;
      s = 1812433253u * (s ^ (s >> 30)) + (uint32_t)i + 1u;
    }
    pos = 624;
  }
  constexpr uint32_t next32() {
    if (pos == 624) {
      for (int i = 0; i < 624; ++i) {
        uint32_t y = (key[i] & 0x80000000u) | (key[(i + 1) % 624] & 0x7fffffffu);
        key[i] = key[(i + 397) % 624] ^ (y >> 1) ^ ((y & 1u) ? 0x9908b0dfu : 0u);
      }
      pos = 0;
    }
    uint32_t y = key[pos++];
    y ^= y >> 11;
    y ^= (y << 7)  & 0x9d2c5680u;
    y ^= (y << 15) & 0xefc60000u;
    y ^= y >> 18;
    return y;
  }
  constexpr double rnd() {
    uint32_t a = next32() >> 5, b = next32() >> 6;
    return (a * 67108864.0 + b) / 9007199254740992.0;
  }
  constexpr uint32_t bounded32(uint32_t rng) {
    if (rng == 0) return 0;
    uint32_t mask = rng;
    mask |= mask >> 1;  mask |= mask >> 2;  mask |= mask >> 4;
    mask |= mask >> 8;  mask |= mask >> 16;
    uint32_t v = next32() & mask;
    while (v > rng) v = next32() & mask;
    return v;
  }
};

constexpr OpList build_ops() {
  OpList ol {};
  ol.n = 0;
  MTc mt {};
  mt.seed(42u);
  for (int l = 0; l < 2; ++l) {
    int i = 0;
    while (i < NQ) {
      if (mt.rnd() > 0.3) {
        int g  = (int)mt.bounded32(2);
        int wq = (int)mt.bounded32(8);
        if (ol.n < MAXRAW) { ol.ops[ol.n] = Op{g, wq, 0, l * NQ + i}; ol.n++; }
        ++i;
      } else {
        int arr[NQ] {};
        for (int t = 0; t < NQ; ++t) arr[t] = t;
        for (int k = NQ - 1; k >= 1; --k) {
          int j = (int)mt.bounded32((uint32_t)k);
          int tmp = arr[k]; arr[k] = arr[j]; arr[j] = tmp;
        }
        if (ol.n < MAXRAW) { ol.ops[ol.n] = Op{3, arr[0], arr[1], 0}; ol.n++; }
      }
    }
  }
  return ol;
}

// ---------- compile-time Heisenberg back-propagation of Z_w ----------
// Per-wire Pauli code: 0=I 1=X 2=Y 3=Z, packed 2 bits/wire in a uint32.
// Backward conjugation: for k = n-1..0, P <- G_k^dag P G_k.
// Rotation R_A(theta)=exp(-i theta A/2), {A,P}!=0:  P -> cos(theta) P + sin(theta) (iAP).
// Final eval on encoded product state RY(pi x_j)|0>: <I>=1 <X>=sin(pi x) <Z>=cos(pi x) <Y>=0.
struct Term { uint32_t cmask, smask, sxm, cxm; int wire, sign; };
struct TermList { int n; int start[NQ + 1]; Term t[MAXT]; };

// CNOT conjugation tables [pc][pt] -> (pc', pt', sign); verified entries incl. XZ->-YY, YY->-XZ
constexpr int kCNc[4][4] = {{0,0,3,3},{1,1,2,2},{2,2,1,1},{3,3,0,0}};
constexpr int kCNt[4][4] = {{0,1,2,3},{1,0,3,2},{1,0,3,2},{0,1,2,3}};
constexpr int kCNs[4][4] = {{1,1,1,1},{1,1,1,-1},{1,1,-1,1},{1,1,1,1}};
// iAP for anticommuting axis A (1=X,2=Y,3=Z) and Pauli P: new P and sign
// iXY=-Z iXZ=+Y | iYX=+Z iYZ=-X | iZX=-Y iZY=+X
constexpr int kIAPn[4][4] = {{0,0,0,0},{0,0,3,2},{0,3,0,1},{0,2,1,0}};
constexpr int kIAPs[4][4] = {{0,0,0,0},{0,0,-1,1},{0,1,0,-1},{0,-1,1,0}};

constexpr void dfs(const OpList& raw, int k, uint32_t ty, int sg,
                   uint32_t cm, uint32_t sm, int wire, TermList& TL) {
  if (k < 0) {
    uint32_t sxm = 0, cxm = 0;
    for (int j = 0; j < NQ; ++j) {
      uint32_t p = (ty >> (2 * j)) & 3u;
      if (p == 2u) return;               // Y factor -> expectation 0, prune
      if (p == 1u) sxm |= 1u << j;
      if (p == 3u) cxm |= 1u << j;
    }
    if (TL.n < MAXT) {
      TL.t[TL.n].cmask = cm; TL.t[TL.n].smask = sm;
      TL.t[TL.n].sxm = sxm;  TL.t[TL.n].cxm = cxm;
      TL.t[TL.n].wire = wire; TL.t[TL.n].sign = sg;
    }
    TL.n = TL.n + 1;                     // keep counting so the assert can fire
    return;
  }
  Op op = raw.ops[k];
  if (op.type == 3) {
    uint32_t pc = (ty >> (2 * op.a)) & 3u;
    uint32_t pt = (ty >> (2 * op.b)) & 3u;
    uint32_t nty = ty & ~((3u << (2 * op.a)) | (3u << (2 * op.b)));
    nty |= (uint32_t)kCNc[pc][pt] << (2 * op.a);
    nty |= (uint32_t)kCNt[pc][pt] << (2 * op.b);
    dfs(raw, k - 1, nty, sg * kCNs[pc][pt], cm, sm, wire, TL);
  } else {
    int A = op.type + 1;                 // RX->X(1) RY->Y(2) RZ->Z(3)
    uint32_t p = (ty >> (2 * op.a)) & 3u;
    if (p == 0u || p == (uint32_t)A) {   // commutes: unchanged, no weight factor
      dfs(raw, k - 1, ty, sg, cm, sm, wire, TL);
      return;
    }
    // cos branch
    dfs(raw, k - 1, ty, sg, cm | (1u << op.widx), sm, wire, TL);
    // sin branch: P_w <- iAP
    uint32_t nty = (ty & ~(3u << (2 * op.a))) | ((uint32_t)kIAPn[A][p] << (2 * op.a));
    dfs(raw, k - 1, nty, sg * kIAPs[A][p], cm, sm | (1u << op.widx), wire, TL);
  }
}

constexpr TermList build_terms() {
  TermList TL {};
  OpList raw = build_ops();
  for (int w = 0; w < NQ; ++w) {
    TL.start[w] = TL.n;
    dfs(raw, raw.n - 1, 3u << (2 * w), 1, 0u, 0u, w, TL);
  }
  TL.start[NQ] = TL.n;
  return TL;
}

constexpr TermList kTL = build_terms();
static_assert(kTL.n <= MAXT, "Pauli term count exceeds MAXT - raise cap");
static_assert(kTL.n >= NQ, "must have at least one term per wire");
constexpr int NT = kTL.n;

// ---------- prep: per-term weight coefficients (all masks compile-time) ----------
template<int Lo, int Hi>
__device__ __forceinline__ void prepr(int s, const float (&cw)[NW], const float (&sw)[NW],
                                      float* __restrict__ coef) {
  if constexpr (Hi - Lo == 1) {
    if (s == Lo) {
      constexpr Term t = kTL.t[Lo];
      float c = (float)t.sign;
#pragma unroll
      for (int k = 0; k < NW; ++k) {
        if ((t.cmask >> k) & 1u) c *= cw[k];
        if ((t.smask >> k) & 1u) c *= sw[k];
      }
      coef[Lo] = c;
    }
  } else {
    constexpr int Mid = Lo + (Hi - Lo) / 2;
    prepr<Lo, Mid>(s, cw, sw, coef);
    prepr<Mid, Hi>(s, cw, sw, coef);
  }
}

__global__ void prep_coef(const float* __restrict__ w, float* __restrict__ coef) {
  int s = blockIdx.x * blockDim.x + threadIdx.x;
  if (s >= NT) return;
  float cw[NW], sw[NW];
#pragma unroll
  for (int k = 0; k < NW; ++k) sincosf(w[k], &sw[k], &cw[k]);   // full angle
  prepr<0, NT>(s, cw, sw, coef);
}

// ---------- prep: per-pixel (cos(pi x), sin(pi x)) table ----------
__global__ void prep_table(const float* __restrict__ x, f2* __restrict__ tab) {
  int i = blockIdx.x * blockDim.x + threadIdx.x;
  if (i < NPIX) {
    float s, c;
    __sincosf(3.14159265358979323846f * x[i], &s, &c);
    f2 v; v.x = c; v.y = s;
    tab[i] = v;
  }
}

// ---------- main: one thread per (channel, site), static polynomial eval ----------
template<uint32_t SXM, uint32_t CXM, int J, bool HAVE>
__device__ __forceinline__ float prodf(float cur, const float (&sx)[NQ], const float (&cx)[NQ]) {
  if constexpr (J == NQ) {
    if constexpr (HAVE) return cur; else return 1.f;
  } else if constexpr ((SXM >> J) & 1u) {
    if constexpr (HAVE) return prodf<SXM, CXM, J + 1, true>(cur * sx[J], sx, cx);
    else                return prodf<SXM, CXM, J + 1, true>(sx[J], sx, cx);
  } else if constexpr ((CXM >> J) & 1u) {
    if constexpr (HAVE) return prodf<SXM, CXM, J + 1, true>(cur * cx[J], sx, cx);
    else                return prodf<SXM, CXM, J + 1, true>(cx[J], sx, cx);
  } else {
    return prodf<SXM, CXM, J + 1, HAVE>(cur, sx, cx);
  }
}

template<int Lo, int Hi>
__device__ __forceinline__ void evalr(const float* __restrict__ coef,
                                      const float (&sx)[NQ], const float (&cx)[NQ],
                                      float (&acc)[NQ]) {
  if constexpr (Hi - Lo == 1) {
    constexpr Term t = kTL.t[Lo];
    float p = prodf<t.sxm, t.cxm, 0, false>(0.f, sx, cx);
    acc[t.wire] = __builtin_fmaf(coef[Lo], p, acc[t.wire]);
  } else {
    constexpr int Mid = Lo + (Hi - Lo) / 2;
    evalr<Lo, Mid>(coef, sx, cx, acc);
    evalr<Mid, Hi>(coef, sx, cx, acc);
  }
}

template<bool TAB>
__global__ __launch_bounds__(TPB) void quanv_pauli(
    const float* __restrict__ x, const f2* __restrict__ tab,
    const float* __restrict__ coef, float* __restrict__ out)
{
  __shared__ float red[SPB][CCH][NQ + 1];
  const int tid  = threadIdx.x;
  const int sl   = tid & (SPB - 1);        // site within block (consecutive lanes -> coalesced)
  const int c    = tid >> 5;               // channel 0..7
  const int site = blockIdx.x * SPB + sl;
  const bool valid = site < NSITES;
  const int ho = site / WO;
  const int wo = site - ho * WO;

  float sx[NQ], cx[NQ];
  if (valid) {
    if constexpr (TAB) {
      const f2* tp = tab + c * (HIMG * WIMG) + ho * WIMG + wo;
#pragma unroll
      for (int m = 0; m < NQ; ++m) {
        f2 v = tp[(m / 3) * WIMG + (m % 3)];
        cx[m] = v.x; sx[m] = v.y;
      }
    } else {
      const float* xp = x + c * (HIMG * WIMG) + ho * WIMG + wo;
#pragma unroll
      for (int m = 0; m < NQ; ++m)
        __sincosf(3.14159265358979323846f * xp[(m / 3) * WIMG + (m % 3)], &sx[m], &cx[m]);
    }
  } else {
#pragma unroll
    for (int m = 0; m < NQ; ++m) { sx[m] = 0.f; cx[m] = 0.f; }
  }

  float acc[NQ];
#pragma unroll
  for (int q = 0; q < NQ; ++q) acc[q] = 0.f;
  evalr<0, NT>(coef, sx, cx, acc);

#pragma unroll
  for (int q = 0; q < NQ; ++q) red[sl][c][q] = acc[q];
  __syncthreads();

  for (int idx = tid; idx < SPB * NQ; idx += TPB) {
    int s2 = idx / NQ;
    int q  = idx - s2 * NQ;
    int gs = blockIdx.x * SPB + s2;
    if (gs < NSITES) {
      float s = 0.f;
#pragma unroll
      for (int cc = 0; cc < CCH; ++cc) s += red[s2][cc][q];
      out[gs * NQ + q] = s;      // raw reshape (Ho,Wo,9) -> flat, same as R1-R5
    }
  }
}

extern "C" void kernel_launch(void* const* d_in, const int* in_sizes, int n_in,
                              void* d_out, int out_size, void* d_ws, size_t ws_size,
                              hipStream_t stream)
{
  const float* x = (const float*)d_in[0];   // (1,8,128,128) f32
  const float* w = (const float*)d_in[1];   // (2,9) f32
  float* out = (float*)d_out;               // (9*126*126) f32

  float* coef = (float*)d_ws;               // NT floats (< 16 KB)
  const size_t tab_off = 65536;
  bool useTab = ws_size >= tab_off + (size_t)NPIX * sizeof(f2);

  prep_coef<<<(NT + 255) / 256, 256, 0, stream>>>(w, coef);
  const int blocks = (NSITES + SPB - 1) / SPB;
  if (useTab) {
    f2* tab = (f2*)((char*)d_ws + tab_off);
    prep_table<<<(NPIX + 255) / 256, 256, 0, stream>>>(x, tab);
    quanv_pauli<true><<<blocks, TPB, 0, stream>>>(x, tab, coef, out);
  } else {
    quanv_pauli<false><<<blocks, TPB, 0, stream>>>(x, nullptr, coef, out);
  }
}

// Round 7
// 12.334 us; speedup vs baseline: 47.5681x; 1.3115x over previous
//
#include <hip/hip_runtime.h>
#include <stdint.h>

#define NQ     9
#define NW     18
#define HIMG   128
#define WIMG   128
#define HO     126
#define WO     126
#define CCH    8
#define NSITES (HO * WO)
#define MAXRAW 64
#define MAXT   4096
#define SPB    32          // sites per block
#define TPB    256         // 32 sites x 8 channels

struct Op { int type, a, b, widx; };     // 0=RX 1=RY 2=RZ 3=CNOT(a=ctrl,b=tgt)
struct OpList { int n; Op ops[MAXRAW]; };

// ---------- constexpr numpy legacy RandomState(42) (bit-exact, verified R1-R6) ----------
struct MTc {
  uint32_t key[624] {};
  int pos = 624;
  constexpr void seed(uint32_t s) {
    for (int i = 0; i < 624; ++i) {
      key[i] = s;
      s = 1812433253u * (s ^ (s >> 30)) + (uint32_t)i + 1u;
    }
    pos = 624;
  }
  constexpr uint32_t next32() {
    if (pos == 624) {
      for (int i = 0; i < 624; ++i) {
        uint32_t y = (key[i] & 0x80000000u) | (key[(i + 1) % 624] & 0x7fffffffu);
        key[i] = key[(i + 397) % 624] ^ (y >> 1) ^ ((y & 1u) ? 0x9908b0dfu : 0u);
      }
      pos = 0;
    }
    uint32_t y = key[pos++];
    y ^= y >> 11;
    y ^= (y << 7)  & 0x9d2c5680u;
    y ^= (y << 15) & 0xefc60000u;
    y ^= y >> 18;
    return y;
  }
  constexpr double rnd() {
    uint32_t a = next32() >> 5, b = next32() >> 6;
    return (a * 67108864.0 + b) / 9007199254740992.0;
  }
  constexpr uint32_t bounded32(uint32_t rng) {
    if (rng == 0) return 0;
    uint32_t mask = rng;
    mask |= mask >> 1;  mask |= mask >> 2;  mask |= mask >> 4;
    mask |= mask >> 8;  mask |= mask >> 16;
    uint32_t v = next32() & mask;
    while (v > rng) v = next32() & mask;
    return v;
  }
};

constexpr OpList build_ops() {
  OpList ol {};
  ol.n = 0;
  MTc mt {};
  mt.seed(42u);
  for (int l = 0; l < 2; ++l) {
    int i = 0;
    while (i < NQ) {
      if (mt.rnd() > 0.3) {
        int g  = (int)mt.bounded32(2);
        int wq = (int)mt.bounded32(8);
        if (ol.n < MAXRAW) { ol.ops[ol.n] = Op{g, wq, 0, l * NQ + i}; ol.n++; }
        ++i;
      } else {
        int arr[NQ] {};
        for (int t = 0; t < NQ; ++t) arr[t] = t;
        for (int k = NQ - 1; k >= 1; --k) {
          int j = (int)mt.bounded32((uint32_t)k);
          int tmp = arr[k]; arr[k] = arr[j]; arr[j] = tmp;
        }
        if (ol.n < MAXRAW) { ol.ops[ol.n] = Op{3, arr[0], arr[1], 0}; ol.n++; }
      }
    }
  }
  return ol;
}

// ---------- compile-time Heisenberg back-propagation of Z_w (verified R6) ----------
struct Term { uint32_t cmask, smask, sxm, cxm; int wire, sign; };
struct TermList { int n; Term t[MAXT]; };

constexpr int kCNc[4][4] = {{0,0,3,3},{1,1,2,2},{2,2,1,1},{3,3,0,0}};
constexpr int kCNt[4][4] = {{0,1,2,3},{1,0,3,2},{1,0,3,2},{0,1,2,3}};
constexpr int kCNs[4][4] = {{1,1,1,1},{1,1,1,-1},{1,1,-1,1},{1,1,1,1}};
constexpr int kIAPn[4][4] = {{0,0,0,0},{0,0,3,2},{0,3,0,1},{0,2,1,0}};
constexpr int kIAPs[4][4] = {{0,0,0,0},{0,0,-1,1},{0,1,0,-1},{0,-1,1,0}};

constexpr void dfs(const OpList& raw, int k, uint32_t ty, int sg,
                   uint32_t cm, uint32_t sm, int wire, TermList& TL) {
  if (k < 0) {
    uint32_t sxm = 0, cxm = 0;
    for (int j = 0; j < NQ; ++j) {
      uint32_t p = (ty >> (2 * j)) & 3u;
      if (p == 2u) return;               // Y factor -> expectation 0, prune
      if (p == 1u) sxm |= 1u << j;
      if (p == 3u) cxm |= 1u << j;
    }
    if (TL.n < MAXT) {
      TL.t[TL.n].cmask = cm; TL.t[TL.n].smask = sm;
      TL.t[TL.n].sxm = sxm;  TL.t[TL.n].cxm = cxm;
      TL.t[TL.n].wire = wire; TL.t[TL.n].sign = sg;
    }
    TL.n = TL.n + 1;
    return;
  }
  Op op = raw.ops[k];
  if (op.type == 3) {
    uint32_t pc = (ty >> (2 * op.a)) & 3u;
    uint32_t pt = (ty >> (2 * op.b)) & 3u;
    uint32_t nty = ty & ~((3u << (2 * op.a)) | (3u << (2 * op.b)));
    nty |= (uint32_t)kCNc[pc][pt] << (2 * op.a);
    nty |= (uint32_t)kCNt[pc][pt] << (2 * op.b);
    dfs(raw, k - 1, nty, sg * kCNs[pc][pt], cm, sm, wire, TL);
  } else {
    int A = op.type + 1;
    uint32_t p = (ty >> (2 * op.a)) & 3u;
    if (p == 0u || p == (uint32_t)A) {
      dfs(raw, k - 1, ty, sg, cm, sm, wire, TL);
      return;
    }
    dfs(raw, k - 1, ty, sg, cm | (1u << op.widx), sm, wire, TL);
    uint32_t nty = (ty & ~(3u << (2 * op.a))) | ((uint32_t)kIAPn[A][p] << (2 * op.a));
    dfs(raw, k - 1, nty, sg * kIAPs[A][p], cm, sm | (1u << op.widx), wire, TL);
  }
}

constexpr TermList build_terms() {
  TermList TL {};
  OpList raw = build_ops();
  for (int w = 0; w < NQ; ++w)
    dfs(raw, raw.n - 1, 3u << (2 * w), 1, 0u, 0u, w, TL);
  return TL;
}

constexpr TermList kTL = build_terms();
static_assert(kTL.n <= MAXT, "Pauli term count exceeds MAXT - raise cap");
static_assert(kTL.n >= NQ, "must have at least one term per wire");
constexpr int NT = kTL.n;

// ---------- merge terms with identical final monomial (wire, sxm, cxm) ----------
struct Groups { int ng; int gid[MAXT]; int key[MAXT]; int wire[MAXT]; uint32_t sxm[MAXT], cxm[MAXT]; };
constexpr Groups build_groups() {
  Groups G {};
  for (int t = 0; t < NT; ++t) {
    int k = (kTL.t[t].wire << 18) | ((int)kTL.t[t].sxm << 9) | (int)kTL.t[t].cxm;
    int f = -1;
    for (int j = 0; j < G.ng; ++j)
      if (G.key[j] == k) { f = j; break; }
    if (f < 0) {
      f = G.ng;
      G.key[f] = k; G.wire[f] = kTL.t[t].wire;
      G.sxm[f] = kTL.t[t].sxm; G.cxm[f] = kTL.t[t].cxm;
      G.ng = G.ng + 1;
    }
    G.gid[t] = f;
  }
  return G;
}
constexpr Groups kG = build_groups();
constexpr int NG = kG.ng;

// sort term indices by group (counting sort)
struct Sorted { int gstart[NG + 1]; int tidx[MAXT]; };
constexpr Sorted build_sorted() {
  Sorted S {};
  int cnt[MAXT] {};
  for (int t = 0; t < NT; ++t) cnt[kG.gid[t]] = cnt[kG.gid[t]] + 1;
  int acc = 0;
  for (int g = 0; g < NG; ++g) { S.gstart[g] = acc; acc += cnt[g]; }
  S.gstart[NG] = acc;
  int pos[MAXT] {};
  for (int g = 0; g < NG; ++g) pos[g] = S.gstart[g];
  for (int t = 0; t < NT; ++t) {
    int g = kG.gid[t];
    S.tidx[pos[g]] = t;
    pos[g] = pos[g] + 1;
  }
  return S;
}
constexpr Sorted kS = build_sorted();

// prep-side constant data: per sorted term, weight masks + sign; per group, member range
struct PrepData { int gstart[NG + 1]; uint32_t cm[NT], sm[NT]; float sgn[NT]; };
constexpr PrepData build_prep() {
  PrepData P {};
  for (int g = 0; g <= NG; ++g) P.gstart[g] = kS.gstart[g];
  for (int s = 0; s < NT; ++s) {
    int t = kS.tidx[s];
    P.cm[s] = kTL.t[t].cmask;
    P.sm[s] = kTL.t[t].smask;
    P.sgn[s] = (float)kTL.t[t].sign;
  }
  return P;
}
__device__ __constant__ PrepData dPD = build_prep();

// ---------- prep kernel: one thread per merged group, runtime member loop ----------
__global__ void prep_groups(const float* __restrict__ w, float* __restrict__ coefg) {
  int g = blockIdx.x * blockDim.x + threadIdx.x;
  float wc[NW], ws[NW];
#pragma unroll
  for (int k = 0; k < NW; ++k) sincosf(w[k], &ws[k], &wc[k]);   // full angle, precise
  if (g < NG) {
    float c = 0.f;
    const int t0 = dPD.gstart[g], t1 = dPD.gstart[g + 1];
    for (int t = t0; t < t1; ++t) {
      float p = dPD.sgn[t];
      const uint32_t cm = dPD.cm[t], sm = dPD.sm[t];
#pragma unroll
      for (int k = 0; k < NW; ++k) {
        if ((cm >> k) & 1u) p *= wc[k];
        if ((sm >> k) & 1u) p *= ws[k];
      }
      c += p;
    }
    coefg[g] = c;
  }
}

// ---------- main: one thread per (channel, site), static monomial eval ----------
template<uint32_t SXM, uint32_t CXM, int J, bool HAVE>
__device__ __forceinline__ float prodf(float cur, const float (&sx)[NQ], const float (&cx)[NQ]) {
  if constexpr (J == NQ) {
    if constexpr (HAVE) return cur; else return 1.f;
  } else if constexpr ((SXM >> J) & 1u) {
    if constexpr (HAVE) return prodf<SXM, CXM, J + 1, true>(cur * sx[J], sx, cx);
    else                return prodf<SXM, CXM, J + 1, true>(sx[J], sx, cx);
  } else if constexpr ((CXM >> J) & 1u) {
    if constexpr (HAVE) return prodf<SXM, CXM, J + 1, true>(cur * cx[J], sx, cx);
    else                return prodf<SXM, CXM, J + 1, true>(cx[J], sx, cx);
  } else {
    return prodf<SXM, CXM, J + 1, HAVE>(cur, sx, cx);
  }
}

template<int Lo, int Hi>
__device__ __forceinline__ void evalg(const float* __restrict__ coefg,
                                      const float (&sx)[NQ], const float (&cx)[NQ],
                                      float (&acc)[NQ]) {
  if constexpr (Hi - Lo == 1) {
    constexpr int w = kG.wire[Lo];
    float p = prodf<kG.sxm[Lo], kG.cxm[Lo], 0, false>(0.f, sx, cx);
    acc[w] = __builtin_fmaf(coefg[Lo], p, acc[w]);
  } else {
    constexpr int Mid = Lo + (Hi - Lo) / 2;
    evalg<Lo, Mid>(coefg, sx, cx, acc);
    evalg<Mid, Hi>(coefg, sx, cx, acc);
  }
}

__global__ __launch_bounds__(TPB) void quanv_pauli(
    const float* __restrict__ x, const float* __restrict__ coefg,
    float* __restrict__ out)
{
  __shared__ float red[SPB][CCH][NQ + 1];
  const int tid  = threadIdx.x;
  const int sl   = tid & (SPB - 1);        // site within block
  const int c    = tid >> 5;               // channel 0..7
  const int site = blockIdx.x * SPB + sl;
  const bool valid = site < NSITES;
  const int ho = site / WO;
  const int wo = site - ho * WO;

  float sx[NQ], cx[NQ];
  if (valid) {
    const float* xp = x + c * (HIMG * WIMG) + ho * WIMG + wo;
#pragma unroll
    for (int m = 0; m < NQ; ++m)
      __sincosf(3.14159265358979323846f * xp[(m / 3) * WIMG + (m % 3)], &sx[m], &cx[m]);
  } else {
#pragma unroll
    for (int m = 0; m < NQ; ++m) { sx[m] = 0.f; cx[m] = 0.f; }
  }

  float acc[NQ];
#pragma unroll
  for (int q = 0; q < NQ; ++q) acc[q] = 0.f;
  evalg<0, NG>(coefg, sx, cx, acc);

#pragma unroll
  for (int q = 0; q < NQ; ++q) red[sl][c][q] = acc[q];
  __syncthreads();

  for (int idx = tid; idx < SPB * NQ; idx += TPB) {
    int s2 = idx / NQ;
    int q  = idx - s2 * NQ;
    int gs = blockIdx.x * SPB + s2;
    if (gs < NSITES) {
      float s = 0.f;
#pragma unroll
      for (int cc = 0; cc < CCH; ++cc) s += red[s2][cc][q];
      out[gs * NQ + q] = s;      // raw reshape (Ho,Wo,9) -> flat
    }
  }
}

extern "C" void kernel_launch(void* const* d_in, const int* in_sizes, int n_in,
                              void* d_out, int out_size, void* d_ws, size_t ws_size,
                              hipStream_t stream)
{
  const float* x = (const float*)d_in[0];   // (1,8,128,128) f32
  const float* w = (const float*)d_in[1];   // (2,9) f32
  float* out = (float*)d_out;               // (9*126*126) f32

  float* coefg = (float*)d_ws;              // NG floats

  prep_groups<<<(NG + 255) / 256, 256, 0, stream>>>(w, coefg);
  const int blocks = (NSITES + SPB - 1) / SPB;
  quanv_pauli<<<blocks, TPB, 0, stream>>>(x, coefg, out);
}

// Round 8
// 10.645 us; speedup vs baseline: 55.1176x; 1.1587x over previous
//
#include <hip/hip_runtime.h>
#include <stdint.h>

#define NQ     9
#define NW     18
#define HIMG   128
#define WIMG   128
#define HO     126
#define WO     126
#define CCH    8
#define NSITES (HO * WO)
#define MAXRAW 64
#define MAXT   4096
#define SPB    32          // sites per block
#define TPB    256         // 32 sites x 8 channels

struct Op { int type, a, b, widx; };     // 0=RX 1=RY 2=RZ 3=CNOT(a=ctrl,b=tgt)
struct OpList { int n; Op ops[MAXRAW]; };

// ---------- constexpr numpy legacy RandomState(42) (bit-exact, verified R1-R7) ----------
struct MTc {
  uint32_t key[624] {};
  int pos = 624;
  constexpr void seed(uint32_t s) {
    for (int i = 0; i < 624; ++i) {
      key[i] = s;
      s = 1812433253u * (s ^ (s >> 30)) + (uint32_t)i + 1u;
    }
    pos = 624;
  }
  constexpr uint32_t next32() {
    if (pos == 624) {
      for (int i = 0; i < 624; ++i) {
        uint32_t y = (key[i] & 0x80000000u) | (key[(i + 1) % 624] & 0x7fffffffu);
        key[i] = key[(i + 397) % 624] ^ (y >> 1) ^ ((y & 1u) ? 0x9908b0dfu : 0u);
      }
      pos = 0;
    }
    uint32_t y = key[pos++];
    y ^= y >> 11;
    y ^= (y << 7)  & 0x9d2c5680u;
    y ^= (y << 15) & 0xefc60000u;
    y ^= y >> 18;
    return y;
  }
  constexpr double rnd() {
    uint32_t a = next32() >> 5, b = next32() >> 6;
    return (a * 67108864.0 + b) / 9007199254740992.0;
  }
  constexpr uint32_t bounded32(uint32_t rng) {
    if (rng == 0) return 0;
    uint32_t mask = rng;
    mask |= mask >> 1;  mask |= mask >> 2;  mask |= mask >> 4;
    mask |= mask >> 8;  mask |= mask >> 16;
    uint32_t v = next32() & mask;
    while (v > rng) v = next32() & mask;
    return v;
  }
};

constexpr OpList build_ops() {
  OpList ol {};
  ol.n = 0;
  MTc mt {};
  mt.seed(42u);
  for (int l = 0; l < 2; ++l) {
    int i = 0;
    while (i < NQ) {
      if (mt.rnd() > 0.3) {
        int g  = (int)mt.bounded32(2);
        int wq = (int)mt.bounded32(8);
        if (ol.n < MAXRAW) { ol.ops[ol.n] = Op{g, wq, 0, l * NQ + i}; ol.n++; }
        ++i;
      } else {
        int arr[NQ] {};
        for (int t = 0; t < NQ; ++t) arr[t] = t;
        for (int k = NQ - 1; k >= 1; --k) {
          int j = (int)mt.bounded32((uint32_t)k);
          int tmp = arr[k]; arr[k] = arr[j]; arr[j] = tmp;
        }
        if (ol.n < MAXRAW) { ol.ops[ol.n] = Op{3, arr[0], arr[1], 0}; ol.n++; }
      }
    }
  }
  return ol;
}

// ---------- compile-time Heisenberg back-propagation of Z_w (verified R6/R7) ----------
struct Term { uint32_t cmask, smask, sxm, cxm; int wire, sign; };
struct TermList { int n; Term t[MAXT]; };

constexpr int kCNc[4][4] = {{0,0,3,3},{1,1,2,2},{2,2,1,1},{3,3,0,0}};
constexpr int kCNt[4][4] = {{0,1,2,3},{1,0,3,2},{1,0,3,2},{0,1,2,3}};
constexpr int kCNs[4][4] = {{1,1,1,1},{1,1,1,-1},{1,1,-1,1},{1,1,1,1}};
constexpr int kIAPn[4][4] = {{0,0,0,0},{0,0,3,2},{0,3,0,1},{0,2,1,0}};
constexpr int kIAPs[4][4] = {{0,0,0,0},{0,0,-1,1},{0,1,0,-1},{0,-1,1,0}};

constexpr void dfs(const OpList& raw, int k, uint32_t ty, int sg,
                   uint32_t cm, uint32_t sm, int wire, TermList& TL) {
  if (k < 0) {
    uint32_t sxm = 0, cxm = 0;
    for (int j = 0; j < NQ; ++j) {
      uint32_t p = (ty >> (2 * j)) & 3u;
      if (p == 2u) return;               // Y factor -> expectation 0, prune
      if (p == 1u) sxm |= 1u << j;
      if (p == 3u) cxm |= 1u << j;
    }
    if (TL.n < MAXT) {
      TL.t[TL.n].cmask = cm; TL.t[TL.n].smask = sm;
      TL.t[TL.n].sxm = sxm;  TL.t[TL.n].cxm = cxm;
      TL.t[TL.n].wire = wire; TL.t[TL.n].sign = sg;
    }
    TL.n = TL.n + 1;
    return;
  }
  Op op = raw.ops[k];
  if (op.type == 3) {
    uint32_t pc = (ty >> (2 * op.a)) & 3u;
    uint32_t pt = (ty >> (2 * op.b)) & 3u;
    uint32_t nty = ty & ~((3u << (2 * op.a)) | (3u << (2 * op.b)));
    nty |= (uint32_t)kCNc[pc][pt] << (2 * op.a);
    nty |= (uint32_t)kCNt[pc][pt] << (2 * op.b);
    dfs(raw, k - 1, nty, sg * kCNs[pc][pt], cm, sm, wire, TL);
  } else {
    int A = op.type + 1;
    uint32_t p = (ty >> (2 * op.a)) & 3u;
    if (p == 0u || p == (uint32_t)A) {
      dfs(raw, k - 1, ty, sg, cm, sm, wire, TL);
      return;
    }
    dfs(raw, k - 1, ty, sg, cm | (1u << op.widx), sm, wire, TL);
    uint32_t nty = (ty & ~(3u << (2 * op.a))) | ((uint32_t)kIAPn[A][p] << (2 * op.a));
    dfs(raw, k - 1, nty, sg * kIAPs[A][p], cm, sm | (1u << op.widx), wire, TL);
  }
}

constexpr TermList build_terms() {
  TermList TL {};
  OpList raw = build_ops();
  for (int w = 0; w < NQ; ++w)
    dfs(raw, raw.n - 1, 3u << (2 * w), 1, 0u, 0u, w, TL);
  return TL;
}

constexpr TermList kTL = build_terms();
static_assert(kTL.n <= MAXT, "Pauli term count exceeds MAXT - raise cap");
static_assert(kTL.n >= NQ, "must have at least one term per wire");
constexpr int NT = kTL.n;

// ---------- merge terms with identical final monomial (wire, sxm, cxm) ----------
struct Groups { int ng; int gid[MAXT]; int key[MAXT]; int wire[MAXT]; uint32_t sxm[MAXT], cxm[MAXT]; };
constexpr Groups build_groups() {
  Groups G {};
  for (int t = 0; t < NT; ++t) {
    int k = (kTL.t[t].wire << 18) | ((int)kTL.t[t].sxm << 9) | (int)kTL.t[t].cxm;
    int f = -1;
    for (int j = 0; j < G.ng; ++j)
      if (G.key[j] == k) { f = j; break; }
    if (f < 0) {
      f = G.ng;
      G.key[f] = k; G.wire[f] = kTL.t[t].wire;
      G.sxm[f] = kTL.t[t].sxm; G.cxm[f] = kTL.t[t].cxm;
      G.ng = G.ng + 1;
    }
    G.gid[t] = f;
  }
  return G;
}
constexpr Groups kG = build_groups();
constexpr int NG = kG.ng;

// sort term indices by group (counting sort)
struct Sorted { int gstart[NG + 1]; int tidx[MAXT]; };
constexpr Sorted build_sorted() {
  Sorted S {};
  int cnt[MAXT] {};
  for (int t = 0; t < NT; ++t) cnt[kG.gid[t]] = cnt[kG.gid[t]] + 1;
  int acc = 0;
  for (int g = 0; g < NG; ++g) { S.gstart[g] = acc; acc += cnt[g]; }
  S.gstart[NG] = acc;
  int pos[MAXT] {};
  for (int g = 0; g < NG; ++g) pos[g] = S.gstart[g];
  for (int t = 0; t < NT; ++t) {
    int g = kG.gid[t];
    S.tidx[pos[g]] = t;
    pos[g] = pos[g] + 1;
  }
  return S;
}
constexpr Sorted kS = build_sorted();

// prep-side constant data: per sorted term, weight masks + sign; per group, member range
struct PrepData { int gstart[NG + 1]; uint32_t cm[NT], sm[NT]; float sgn[NT]; };
constexpr PrepData build_prep() {
  PrepData P {};
  for (int g = 0; g <= NG; ++g) P.gstart[g] = kS.gstart[g];
  for (int s = 0; s < NT; ++s) {
    int t = kS.tidx[s];
    P.cm[s] = kTL.t[t].cmask;
    P.sm[s] = kTL.t[t].smask;
    P.sgn[s] = (float)kTL.t[t].sign;
  }
  return P;
}
__device__ __constant__ PrepData dPD = build_prep();

// ---------- monomial eval helpers (all masks compile-time) ----------
template<uint32_t SXM, uint32_t CXM, int J, bool HAVE>
__device__ __forceinline__ float prodf(float cur, const float (&sx)[NQ], const float (&cx)[NQ]) {
  if constexpr (J == NQ) {
    if constexpr (HAVE) return cur; else return 1.f;
  } else if constexpr ((SXM >> J) & 1u) {
    if constexpr (HAVE) return prodf<SXM, CXM, J + 1, true>(cur * sx[J], sx, cx);
    else                return prodf<SXM, CXM, J + 1, true>(sx[J], sx, cx);
  } else if constexpr ((CXM >> J) & 1u) {
    if constexpr (HAVE) return prodf<SXM, CXM, J + 1, true>(cur * cx[J], sx, cx);
    else                return prodf<SXM, CXM, J + 1, true>(cx[J], sx, cx);
  } else {
    return prodf<SXM, CXM, J + 1, HAVE>(cur, sx, cx);
  }
}

template<int Lo, int Hi>
__device__ __forceinline__ void evalg(const float* __restrict__ coefg,
                                      const float (&sx)[NQ], const float (&cx)[NQ],
                                      float (&acc)[NQ]) {
  if constexpr (Hi - Lo == 1) {
    constexpr int w = kG.wire[Lo];
    float p = prodf<kG.sxm[Lo], kG.cxm[Lo], 0, false>(0.f, sx, cx);
    acc[w] = __builtin_fmaf(coefg[Lo], p, acc[w]);
  } else {
    constexpr int Mid = Lo + (Hi - Lo) / 2;
    evalg<Lo, Mid>(coefg, sx, cx, acc);
    evalg<Mid, Hi>(coefg, sx, cx, acc);
  }
}

// ---------- single fused kernel ----------
__global__ __launch_bounds__(TPB) void quanv_fused(
    const float* __restrict__ x, const float* __restrict__ w,
    float* __restrict__ out)
{
  __shared__ float lcoef[NG];
  __shared__ float red[SPB][CCH][NQ + 1];

  const int tid  = threadIdx.x;

  // ---- phase 1: per-block redundant coefficient computation (one thread/group)
  if (tid < NG) {
    float wc[NW], ws[NW];
#pragma unroll
    for (int k = 0; k < NW; ++k) sincosf(w[k], &ws[k], &wc[k]);   // full angle, precise
    for (int g = tid; g < NG; g += TPB) {
      float c = 0.f;
      const int t0 = dPD.gstart[g], t1 = dPD.gstart[g + 1];
      for (int t = t0; t < t1; ++t) {
        float p = dPD.sgn[t];
        const uint32_t cm = dPD.cm[t], sm = dPD.sm[t];
#pragma unroll
        for (int k = 0; k < NW; ++k) {
          if ((cm >> k) & 1u) p *= wc[k];
          if ((sm >> k) & 1u) p *= ws[k];
        }
        c += p;
      }
      lcoef[g] = c;
    }
  }

  // ---- phase 2: per-(channel,site) pixel trig
  const int sl   = tid & (SPB - 1);        // site within block
  const int c    = tid >> 5;               // channel 0..7
  const int site = blockIdx.x * SPB + sl;
  const bool valid = site < NSITES;
  const int ho = site / WO;
  const int wo = site - ho * WO;

  float sx[NQ], cx[NQ];
  if (valid) {
    const float* xp = x + c * (HIMG * WIMG) + ho * WIMG + wo;
#pragma unroll
    for (int m = 0; m < NQ; ++m)
      __sincosf(3.14159265358979323846f * xp[(m / 3) * WIMG + (m % 3)], &sx[m], &cx[m]);
  } else {
#pragma unroll
    for (int m = 0; m < NQ; ++m) { sx[m] = 0.f; cx[m] = 0.f; }
  }

  __syncthreads();   // lcoef ready

  // ---- phase 3: static monomial eval (coefs broadcast from LDS)
  float acc[NQ];
#pragma unroll
  for (int q = 0; q < NQ; ++q) acc[q] = 0.f;
  evalg<0, NG>(lcoef, sx, cx, acc);

#pragma unroll
  for (int q = 0; q < NQ; ++q) red[sl][c][q] = acc[q];
  __syncthreads();

  // ---- phase 4: channel-sum and store
  for (int idx = tid; idx < SPB * NQ; idx += TPB) {
    int s2 = idx / NQ;
    int q  = idx - s2 * NQ;
    int gs = blockIdx.x * SPB + s2;
    if (gs < NSITES) {
      float s = 0.f;
#pragma unroll
      for (int cc = 0; cc < CCH; ++cc) s += red[s2][cc][q];
      out[gs * NQ + q] = s;      // raw reshape (Ho,Wo,9) -> flat
    }
  }
}

extern "C" void kernel_launch(void* const* d_in, const int* in_sizes, int n_in,
                              void* d_out, int out_size, void* d_ws, size_t ws_size,
                              hipStream_t stream)
{
  const float* x = (const float*)d_in[0];   // (1,8,128,128) f32
  const float* w = (const float*)d_in[1];   // (2,9) f32
  float* out = (float*)d_out;               // (9*126*126) f32

  const int blocks = (NSITES + SPB - 1) / SPB;
  quanv_fused<<<blocks, TPB, 0, stream>>>(x, w, out);
}